// Round 10
// baseline (410.870 us; speedup 1.0000x reference)
//
#include <hip/hip_runtime.h>
#include <cstdint>
#include <cstddef>

#define NNODE 8192
#define NEDGE 262144

typedef __attribute__((ext_vector_type(8))) short bf16x8;
typedef __attribute__((ext_vector_type(4))) float f32x4;

// ---------------- bf16 split helpers ----------------
__device__ __forceinline__ unsigned short f2bf_rn(float x) {
    unsigned u = __float_as_uint(x);
    u = (u + 0x7FFFu + ((u >> 16) & 1u)) >> 16;
    return (unsigned short)u;
}
__device__ __forceinline__ float bf2f(unsigned short h) {
    return __uint_as_float(((unsigned)h) << 16);
}

__device__ __forceinline__ void gload16(const char* gp, char* lp) {
    __builtin_amdgcn_global_load_lds((const __attribute__((address_space(1))) void*)gp,
                                     (__attribute__((address_space(3))) void*)lp, 16, 0, 0);
}

// ---------------- CSR kernels ----------------

__global__ void k_count(const int* __restrict__ dst, int* __restrict__ cnt, int n) {
    int i = blockIdx.x * blockDim.x + threadIdx.x;
    if (i < n) atomicAdd(&cnt[dst[i]], 1);
}

__global__ __launch_bounds__(256) void k_scan(const int* __restrict__ cnt,
                                              int* __restrict__ row_start,
                                              int* __restrict__ cursor,
                                              float* __restrict__ dinv) {
    __shared__ int part[256];
    const int tid = threadIdx.x;
    const int PER = NNODE / 256;  // 32
    const int base = tid * PER;
    int loc[PER];
    int sum = 0;
#pragma unroll
    for (int i = 0; i < PER; ++i) { loc[i] = cnt[base + i]; sum += loc[i]; }
    part[tid] = sum;
    __syncthreads();
    if (tid == 0) {
        int r = 0;
        for (int i = 0; i < 256; ++i) { int t = part[i]; part[i] = r; r += t; }
    }
    __syncthreads();
    int run = part[tid];
#pragma unroll
    for (int i = 0; i < PER; ++i) {
        row_start[base + i] = run;
        cursor[base + i] = run;
        dinv[base + i] = rsqrtf((float)loc[i] + 1.0f);  // deg = in-degree + self loop
        run += loc[i];
    }
    if (tid == 255) row_start[NNODE] = run;
}

__global__ void k_fill_csr2(const int* __restrict__ src, const int* __restrict__ dst,
                            int* __restrict__ cursor, const float* __restrict__ dinv,
                            int* __restrict__ slist, float* __restrict__ wlist, int n) {
    int e = blockIdx.x * blockDim.x + threadIdx.x;
    if (e < n) {
        int d = dst[e];
        int s = src[e];
        int pos = atomicAdd(&cursor[d], 1);
        slist[pos] = s;
        wlist[pos] = dinv[s] * dinv[d];
    }
}

// ---------------- mega prep kernel (also zeroes cnt) ----------------
__device__ __forceinline__ void split_wt_tile(const float* __restrict__ W, int K, int N,
                                              int k0, int n0,
                                              unsigned short* __restrict__ Oh,
                                              unsigned short* __restrict__ Ol,
                                              float (*t)[33]) {
    const int c = threadIdx.x & 31, r8 = threadIdx.x >> 5;
#pragma unroll
    for (int i = 0; i < 4; ++i) {
        int r = r8 + i * 8;
        t[r][c] = W[(size_t)(k0 + r) * N + n0 + c];
    }
    __syncthreads();
#pragma unroll
    for (int i = 0; i < 4; ++i) {
        int r = r8 + i * 8;
        float x = t[c][r];
        unsigned short h = f2bf_rn(x);
        Oh[(size_t)(n0 + r) * K + k0 + c] = h;
        Ol[(size_t)(n0 + r) * K + k0 + c] = f2bf_rn(x - bf2f(h));
    }
}

__global__ __launch_bounds__(256) void k_prep(
    const float* __restrict__ x_self, const float* __restrict__ x_neighbor,
    const float* __restrict__ w_in_self, const float* __restrict__ w_out_self,
    const float* __restrict__ w_out, const float* __restrict__ gw1,
    const float* __restrict__ gw2, const float* __restrict__ gb1,
    unsigned short* __restrict__ xsh, unsigned short* __restrict__ xsl,
    unsigned short* __restrict__ xnh, unsigned short* __restrict__ xnl,
    unsigned short* __restrict__ wAt_h, unsigned short* __restrict__ wAt_l,
    unsigned short* __restrict__ wost_h, unsigned short* __restrict__ wost_l,
    unsigned short* __restrict__ wot_h, unsigned short* __restrict__ wot_l,
    float* __restrict__ bc, int* __restrict__ cnt) {
    __shared__ float t[32][33];
    const int b = blockIdx.x;
    const int tid = threadIdx.x;
    if (b < 8192) {  // splits
        const float* src = (b < 4096) ? x_self : x_neighbor;
        unsigned short* oh = (b < 4096) ? xsh : xnh;
        unsigned short* ol = (b < 4096) ? xsl : xnl;
        const int i = (b & 4095) * 256 + tid;
        float4 v = ((const float4*)src)[i];
        float x[4] = {v.x, v.y, v.z, v.w};
        unsigned short h[4], l[4];
#pragma unroll
        for (int j = 0; j < 4; ++j) {
            h[j] = f2bf_rn(x[j]);
            l[j] = f2bf_rn(x[j] - bf2f(h[j]));
        }
        ((ushort4*)oh)[i] = make_ushort4(h[0], h[1], h[2], h[3]);
        ((ushort4*)ol)[i] = make_ushort4(l[0], l[1], l[2], l[3]);
    } else if (b < 8448) {
        const int b2 = b - 8192;
        split_wt_tile(w_in_self, 512, 512, (b2 & 15) * 32, (b2 >> 4) * 32, wAt_h, wAt_l, t);
    } else if (b < 8576) {  // Wc = gw1 @ gw2 on the fly
        const int b3 = b - 8448;
        const int k0 = (b3 & 15) * 32, n0 = (b3 >> 4) * 32;
        const int nloc = tid & 31, kg = tid >> 5;
        float a[4] = {0.f, 0.f, 0.f, 0.f};
        for (int c = 0; c < 512; ++c) {
            float g2v = gw2[(size_t)c * 256 + n0 + nloc];
#pragma unroll
            for (int i = 0; i < 4; ++i)
                a[i] += gw1[(size_t)(k0 + kg * 4 + i) * 512 + c] * g2v;
        }
#pragma unroll
        for (int i = 0; i < 4; ++i) {
            unsigned short hh = f2bf_rn(a[i]);
            wAt_h[(size_t)(512 + n0 + nloc) * 512 + k0 + kg * 4 + i] = hh;
            wAt_l[(size_t)(512 + n0 + nloc) * 512 + k0 + kg * 4 + i] = f2bf_rn(a[i] - bf2f(hh));
        }
    } else if (b < 8832) {
        const int b4 = b - 8576;
        split_wt_tile(w_out_self, 1024, 256, (b4 & 31) * 32, (b4 >> 5) * 32, wost_h, wost_l, t);
    } else if (b < 9024) {
        const int b5 = b - 8832;
        split_wt_tile(w_out, 768, 256, (b5 % 24) * 32, (b5 / 24) * 32, wot_h, wot_l, t);
    } else if (b == 9024) {
        float a = 0.0f;
        for (int c = 0; c < 512; ++c) a += gb1[c] * gw2[(size_t)c * 256 + tid];
        bc[tid] = a;
    } else {  // zero cnt: blocks 9025..9056
        cnt[(b - 9025) * 256 + tid] = 0;
    }
}

// ---------------- shared GEMM pieces (128x64 tile, 4 waves, BK=32) ----------------
__device__ __forceinline__ void stage_g(char* buf,
                                        const char* aH, const char* aL, size_t strA,
                                        const char* bH, const char* bL, size_t strB,
                                        int rloc, int w) {
#pragma unroll
    for (int i = 0; i < 2; ++i) {
        const size_t r = (size_t)(rloc + i * 64);
        char* lp = buf + i * 4096 + w * 1024;
        gload16(aH + r * strA, lp);
        gload16(aL + r * strA, lp + 8192);
    }
    gload16(bH + (size_t)rloc * strB, buf + 16384 + w * 1024);
    gload16(bL + (size_t)rloc * strB, buf + 20480 + w * 1024);
}

__device__ __forceinline__ void core_2x4(const char* cur, int w, int sread, int lane,
                                         f32x4 acc[2][4]) {
    bf16x8 ah[2], al[2], bh[4], bl[4];
#pragma unroll
    for (int m = 0; m < 2; ++m) {
        const int row = w * 32 + m * 16 + (lane & 15);
        ah[m] = *(const bf16x8*)(cur + row * 64 + sread);
        al[m] = *(const bf16x8*)(cur + 8192 + row * 64 + sread);
    }
#pragma unroll
    for (int n = 0; n < 4; ++n) {
        const int row = n * 16 + (lane & 15);
        bh[n] = *(const bf16x8*)(cur + 16384 + row * 64 + sread);
        bl[n] = *(const bf16x8*)(cur + 20480 + row * 64 + sread);
    }
#pragma unroll
    for (int m = 0; m < 2; ++m)
#pragma unroll
        for (int n = 0; n < 4; ++n) {
            acc[m][n] = __builtin_amdgcn_mfma_f32_16x16x32_bf16(ah[m], bh[n], acc[m][n], 0, 0, 0);
            acc[m][n] = __builtin_amdgcn_mfma_f32_16x16x32_bf16(ah[m], bl[n], acc[m][n], 0, 0, 0);
            acc[m][n] = __builtin_amdgcn_mfma_f32_16x16x32_bf16(al[m], bh[n], acc[m][n], 0, 0, 0);
        }
}

// ---------------- GEMM-A: xs @ [Win | Wc] -> l1 (relu,split) + hc (fp32) ----------------
// 1D grid 768 = 8 x 96, XCD-chunked. Counted-vmcnt depth-2 pipeline.
__global__ __launch_bounds__(256) void k_gemm128_A(
    const unsigned short* __restrict__ xsh, const unsigned short* __restrict__ xsl,
    const unsigned short* __restrict__ wAt_h, const unsigned short* __restrict__ wAt_l,
    const float* __restrict__ bias,
    unsigned short* __restrict__ l1h, unsigned short* __restrict__ l1l,
    float* __restrict__ hc) {
    __shared__ __align__(16) char smem[49152];
    const int tid = threadIdx.x, lane = tid & 63, w = tid >> 6;
    const int t0 = blockIdx.x;
    const int s = (t0 & 7) * 96 + (t0 >> 3);
    const int bm = (s / 12) * 128, bn = (s % 12) * 64;
    const int rloc = w * 16 + (lane >> 2);
    const int swz_src = ((lane & 3) ^ ((lane >> 3) & 3)) * 16;
    const int sread = ((lane >> 4) ^ ((lane >> 1) & 3)) * 16;
    const char* Ah = (const char*)xsh + (size_t)bm * 1024 + swz_src;
    const char* Al = (const char*)xsl + (size_t)bm * 1024 + swz_src;
    const char* Bh = (const char*)wAt_h + (size_t)bn * 1024 + swz_src;
    const char* Bl = (const char*)wAt_l + (size_t)bn * 1024 + swz_src;

    f32x4 acc[2][4] = {};
    stage_g(smem,         Ah,      Al,      1024, Bh,      Bl,      1024, rloc, w);
    stage_g(smem + 24576, Ah + 64, Al + 64, 1024, Bh + 64, Bl + 64, 1024, rloc, w);
    for (int ks = 0; ks < 16; ++ks) {
        if (ks < 15) asm volatile("s_waitcnt vmcnt(6)" ::: "memory");
        else         asm volatile("s_waitcnt vmcnt(0)" ::: "memory");
        __builtin_amdgcn_s_barrier();
        __builtin_amdgcn_sched_barrier(0);
        core_2x4(smem + (ks & 1) * 24576, w, sread, lane, acc);
        __builtin_amdgcn_sched_barrier(0);
        __builtin_amdgcn_s_barrier();
        if (ks < 14) {
            const int kb = (ks + 2) * 64;
            stage_g(smem + (ks & 1) * 24576, Ah + kb, Al + kb, 1024,
                    Bh + kb, Bl + kb, 1024, rloc, w);
        }
    }

    const int rj = (lane >> 4) * 4, cc = lane & 15;
#pragma unroll
    for (int m = 0; m < 2; ++m) {
#pragma unroll
        for (int n = 0; n < 4; ++n) {
            const int col = bn + n * 16 + cc;
#pragma unroll
            for (int j = 0; j < 4; ++j) {
                const int row = bm + w * 32 + m * 16 + rj + j;
                float x = acc[m][n][j];
                if (col < 512) {
                    x += bias[col];
                    x = fmaxf(x, 0.0f);
                    unsigned short h = f2bf_rn(x);
                    l1h[(size_t)row * 512 + col] = h;
                    l1l[(size_t)row * 512 + col] = f2bf_rn(x - bf2f(h));
                } else {
                    hc[(size_t)row * 256 + (col - 512)] = x;
                }
            }
        }
    }
}

// ---------------- GEMM-Z: z halves, concat-K. 1D grid 512 = 8 x 64, counted-vmcnt ----------------
__global__ __launch_bounds__(256) void k_gemm128_Z(
    const unsigned short* __restrict__ xsh, const unsigned short* __restrict__ xsl,
    const unsigned short* __restrict__ l1h, const unsigned short* __restrict__ l1l,
    const unsigned short* __restrict__ xnh, const unsigned short* __restrict__ xnl,
    const unsigned short* __restrict__ g2h, const unsigned short* __restrict__ g2l,
    const unsigned short* __restrict__ wost_h, const unsigned short* __restrict__ wost_l,
    const unsigned short* __restrict__ wot_h, const unsigned short* __restrict__ wot_l,
    const float* __restrict__ b_out_self, const float* __restrict__ b_out,
    unsigned short* __restrict__ zhi, unsigned short* __restrict__ zlo) {
    __shared__ __align__(16) char smem[49152];
    const int t0 = blockIdx.x;
    const int s = (t0 & 7) * 64 + (t0 >> 3);
    const int half = s >> 8;
    const int rem = s & 255;
    const int bn = (rem & 3) * 64;
    const int bm = (rem >> 2) * 128;
    const int tid = threadIdx.x, lane = tid & 63, w = tid >> 6;
    const int rloc = w * 16 + (lane >> 2);
    const int swz_src = ((lane & 3) ^ ((lane >> 3) & 3)) * 16;
    const int sread = ((lane >> 4) ^ ((lane >> 1) & 3)) * 16;

    const unsigned short *A1h, *A1l, *A2h, *A2l, *Wh, *Wl;
    const float* bias;
    int Ktot;
    size_t strA2, strB;
    if (half == 0) {
        A1h = xsh; A1l = xsl; A2h = l1h; A2l = l1l; strA2 = 1024;
        Wh = wost_h; Wl = wost_l; strB = 2048; Ktot = 1024; bias = b_out_self;
    } else {
        A1h = xnh; A1l = xnl; A2h = g2h; A2l = g2l; strA2 = 512;
        Wh = wot_h; Wl = wot_l; strB = 1536; Ktot = 768; bias = b_out;
    }
    const int nsteps = Ktot / 32;
    const char* Bh = (const char*)Wh + (size_t)bn * strB + swz_src;
    const char* Bl = (const char*)Wl + (size_t)bn * strB + swz_src;

    auto asrc = [&](int k0, const char*& sh, const char*& sl, size_t& st) {
        if (k0 < 512) {
            sh = (const char*)A1h + (size_t)bm * 1024 + (size_t)k0 * 2 + swz_src;
            sl = (const char*)A1l + (size_t)bm * 1024 + (size_t)k0 * 2 + swz_src;
            st = 1024;
        } else {
            sh = (const char*)A2h + (size_t)bm * strA2 + (size_t)(k0 - 512) * 2 + swz_src;
            sl = (const char*)A2l + (size_t)bm * strA2 + (size_t)(k0 - 512) * 2 + swz_src;
            st = strA2;
        }
    };

    f32x4 acc[2][4] = {};
    {
        const char *sh, *sl; size_t st;
        asrc(0, sh, sl, st);
        stage_g(smem, sh, sl, st, Bh, Bl, strB, rloc, w);
        asrc(32, sh, sl, st);
        stage_g(smem + 24576, sh, sl, st, Bh + 64, Bl + 64, strB, rloc, w);
    }
    for (int ks = 0; ks < nsteps; ++ks) {
        if (ks < nsteps - 1) asm volatile("s_waitcnt vmcnt(6)" ::: "memory");
        else                 asm volatile("s_waitcnt vmcnt(0)" ::: "memory");
        __builtin_amdgcn_s_barrier();
        __builtin_amdgcn_sched_barrier(0);
        core_2x4(smem + (ks & 1) * 24576, w, sread, lane, acc);
        __builtin_amdgcn_sched_barrier(0);
        __builtin_amdgcn_s_barrier();
        if (ks + 2 < nsteps) {
            const char *sh, *sl; size_t st;
            asrc((ks + 2) * 32, sh, sl, st);
            stage_g(smem + (ks & 1) * 24576, sh, sl, st,
                    Bh + (size_t)(ks + 2) * 64, Bl + (size_t)(ks + 2) * 64, strB, rloc, w);
        }
    }

    const int rj = (lane >> 4) * 4, cc = lane & 15;
    const int zoff = half * 256;
#pragma unroll
    for (int m = 0; m < 2; ++m) {
#pragma unroll
        for (int n = 0; n < 4; ++n) {
            const int col = bn + n * 16 + cc;  // 0..255 within half
            const float bv = bias[col];
#pragma unroll
            for (int j = 0; j < 4; ++j) {
                const int row = bm + w * 32 + m * 16 + rj + j;
                float x = acc[m][n][j] + bv;
                unsigned short h = f2bf_rn(x);
                zhi[(size_t)row * 512 + zoff + col] = h;
                zlo[(size_t)row * 512 + zoff + col] = f2bf_rn(x - bf2f(h));
            }
        }
    }
}

// ---------------- GCN aggregation, unroll-8 gathers ----------------
template <int MODE>
__global__ __launch_bounds__(256) void k_agg2(
    const int* __restrict__ row_start, const int* __restrict__ slist,
    const float* __restrict__ wlist, const float* __restrict__ dinv,
    const float* __restrict__ h,
    const float* __restrict__ bc, const float* __restrict__ b2,
    float* __restrict__ outf,
    unsigned short* __restrict__ oh, unsigned short* __restrict__ ol) {
    const int n = blockIdx.x;
    const int c = threadIdx.x;
    const float di = dinv[n];
    float acc = di * di * h[(size_t)n * 256 + c];
    float sv = di * di;
    const int e0 = row_start[n], e1 = row_start[n + 1];
    int j = e0;
    for (; j + 8 <= e1; j += 8) {
        int ss[8];
        float ww[8], vv[8];
#pragma unroll
        for (int u = 0; u < 8; ++u) { ss[u] = slist[j + u]; ww[u] = wlist[j + u]; }
#pragma unroll
        for (int u = 0; u < 8; ++u) vv[u] = h[(size_t)ss[u] * 256 + c];
#pragma unroll
        for (int u = 0; u < 8; ++u) {
            acc += ww[u] * vv[u];
            if (MODE) sv += ww[u];
        }
    }
    for (; j < e1; ++j) {
        const float wv = wlist[j];
        acc += wv * h[(size_t)slist[j] * 256 + c];
        if (MODE) sv += wv;
    }
    if (MODE == 0) {
        outf[(size_t)n * 256 + c] = acc;
    } else {
        float x = acc + sv * bc[c] + b2[c];
        unsigned short hb = f2bf_rn(x);
        oh[(size_t)n * 256 + c] = hb;
        ol[(size_t)n * 256 + c] = f2bf_rn(x - bf2f(hb));
    }
}

// ---------------- out = sigmoid(Z Z^T), 128x256 rect tiles, counted-vmcnt depth-2 ----------------
// Tiles (I,J): rows I*128..+127, cols J*256..+255, computed for I >= 2J (1056 tiles).
// Full tile written directly; full mirror always written (identical values on overlap).
// 4 waves, wave tile 128x64 (8x4 units), acc[8][4]. LDS/buf 48KB: Ah 8K | Al 8K | Bh 16K | Bl 16K.
__global__ __launch_bounds__(256, 1) void k_zzt_rect(const unsigned short* __restrict__ zhi,
                                                     const unsigned short* __restrict__ zlo,
                                                     float* __restrict__ out) {
    __shared__ __align__(16) char smem[98304];  // 2 x 48KB
    const int tid = threadIdx.x;
    const int lane = tid & 63;
    const int w = tid >> 6;

    // XCD swizzle (1056 = 8 x 132, bijective), then decode p -> (I,J), I >= 2J
    const int t0 = blockIdx.x;
    int p = (t0 & 7) * 132 + (t0 >> 3);
    int J = 0;
    while (p >= 64 - 2 * J) { p -= 64 - 2 * J; ++J; }
    const int I = 2 * J + p;

    const char* pp0 = (const char*)zhi + (size_t)(I * 128) * 1024;  // A hi
    const char* pp1 = (const char*)zlo + (size_t)(I * 128) * 1024;  // A lo
    const char* pp2 = (const char*)zhi + (size_t)(J * 256) * 1024;  // B hi
    const char* pp3 = (const char*)zlo + (size_t)(J * 256) * 1024;  // B lo

    const int swz_src = ((lane & 3) ^ ((lane >> 3) & 3)) * 16;
    const int sread = ((lane >> 4) ^ ((lane >> 1) & 3)) * 16;

    // stage one K32 step: 48 chunks of 16 rows (A: 8 hi + 8 lo, B: 16 hi + 16 lo);
    // wave w owns chunks w*12..w*12+11 -> 12 gload16 per wave.
    auto STAGE = [&](int buf, int kt) {
        const int kb = kt * 64;
        char* base = smem + buf * 49152;
        const char* pp[4] = {pp0, pp1, pp2, pp3};
#pragma unroll
        for (int jj = 0; jj < 12; ++jj) {
            const int c = w * 12 + jj;
            int q, ci;
            char* dst;
            if (c < 16) {         // A chunks
                q = c >> 3; ci = c & 7;
                dst = base + q * 8192 + ci * 1024;
            } else {              // B chunks
                const int c2 = c - 16;
                q = 2 + (c2 >> 4); ci = c2 & 15;
                dst = base + 16384 + (c2 >> 4) * 16384 + ci * 1024;
            }
            gload16(pp[q] + (size_t)(ci * 16 + (lane >> 2)) * 1024 + kb + swz_src, dst);
        }
    };

    f32x4 acc[8][4] = {};

    STAGE(0, 0);
    STAGE(1, 1);

    for (int ks = 0; ks < 16; ++ks) {
        if (ks < 15) asm volatile("s_waitcnt vmcnt(12)" ::: "memory");
        else         asm volatile("s_waitcnt vmcnt(0)" ::: "memory");
        __builtin_amdgcn_s_barrier();
        __builtin_amdgcn_sched_barrier(0);
        const char* cur = smem + (ks & 1) * 49152;

        bf16x8 bh[4], bl[4];
#pragma unroll
        for (int n = 0; n < 4; ++n) {
            const int cr = w * 64 + n * 16 + (lane & 15);
            bh[n] = *(const bf16x8*)(cur + 16384 + cr * 64 + sread);
            bl[n] = *(const bf16x8*)(cur + 32768 + cr * 64 + sread);
        }
#pragma unroll
        for (int m = 0; m < 8; ++m) {
            const int row = m * 16 + (lane & 15);
            bf16x8 ah = *(const bf16x8*)(cur + row * 64 + sread);
            bf16x8 al = *(const bf16x8*)(cur + 8192 + row * 64 + sread);
            __builtin_amdgcn_s_setprio(1);
#pragma unroll
            for (int n = 0; n < 4; ++n) {
                acc[m][n] = __builtin_amdgcn_mfma_f32_16x16x32_bf16(ah, bh[n], acc[m][n], 0, 0, 0);
                acc[m][n] = __builtin_amdgcn_mfma_f32_16x16x32_bf16(ah, bl[n], acc[m][n], 0, 0, 0);
                acc[m][n] = __builtin_amdgcn_mfma_f32_16x16x32_bf16(al, bh[n], acc[m][n], 0, 0, 0);
            }
            __builtin_amdgcn_s_setprio(0);
        }
        __builtin_amdgcn_sched_barrier(0);
        __builtin_amdgcn_s_barrier();
        if (ks < 14) STAGE(ks & 1, ks + 2);
    }

    // epilogue: sigmoid once; direct tile + full mirror (NT stores)
    const int rj = (lane >> 4) * 4;
    const int cc = lane & 15;
#pragma unroll
    for (int m = 0; m < 8; ++m) {
#pragma unroll
        for (int n = 0; n < 4; ++n) {
            float s[4];
#pragma unroll
            for (int j = 0; j < 4; ++j)
                s[j] = 1.0f / (1.0f + __expf(-acc[m][n][j]));
            const int gr0 = I * 128 + m * 16 + rj;
            const int gc  = J * 256 + w * 64 + n * 16 + cc;
#pragma unroll
            for (int j = 0; j < 4; ++j)
                __builtin_nontemporal_store(s[j], out + (size_t)(gr0 + j) * NNODE + gc);
            f32x4 v = {s[0], s[1], s[2], s[3]};
            __builtin_nontemporal_store(v, (f32x4*)(out + (size_t)gc * NNODE + gr0));
        }
    }
}

// ---------------- launch ----------------
extern "C" void kernel_launch(void* const* d_in, const int* in_sizes, int n_in,
                              void* d_out, int out_size, void* d_ws, size_t ws_size,
                              hipStream_t stream) {
    const float* x_self     = (const float*)d_in[0];
    const float* x_neighbor = (const float*)d_in[1];
    const int*   ei         = (const int*)d_in[2];
    const float* w_in_self  = (const float*)d_in[3];
    const float* b_in_self  = (const float*)d_in[4];
    const float* w_out_self = (const float*)d_in[5];
    const float* b_out_self = (const float*)d_in[6];
    const float* gw1        = (const float*)d_in[7];
    const float* gb1        = (const float*)d_in[8];
    const float* gw2        = (const float*)d_in[9];
    const float* gb2        = (const float*)d_in[10];
    const float* w_out      = (const float*)d_in[11];
    const float* b_out      = (const float*)d_in[12];
    float* out = (float*)d_out;

    char* ws = (char*)d_ws;
    const size_t MB = 1024 * 1024;
    const size_t KB = 1024;
    int*   cnt       = (int*)(ws + 0);
    int*   row_start = (int*)(ws + 32 * KB);
    int*   cursor    = (int*)(ws + 96 * KB);
    float* dinv      = (float*)(ws + 128 * KB);
    float* bc        = (float*)(ws + 192 * KB);
    int*   slist     = (int*)(ws + 2 * MB);
    float* wlist     = (float*)(ws + 3 * MB);
    unsigned short* xsh = (unsigned short*)(ws + 4 * MB);
    unsigned short* xsl = (unsigned short*)(ws + 12 * MB);
    unsigned short* xnh = (unsigned short*)(ws + 20 * MB);
    unsigned short* xnl = (unsigned short*)(ws + 28 * MB);
    unsigned short* l1h = (unsigned short*)(ws + 36 * MB);
    unsigned short* l1l = (unsigned short*)(ws + 44 * MB);
    float*          hc  = (float*)(ws + 52 * MB);   // 8 MB fp32 [8192,256]
    float*          t1  = (float*)(ws + 60 * MB);   // 8 MB fp32
    unsigned short* g2h = (unsigned short*)(ws + 68 * MB);
    unsigned short* g2l = (unsigned short*)(ws + 72 * MB);
    unsigned short* zhi = (unsigned short*)(ws + 76 * MB);
    unsigned short* zlo = (unsigned short*)(ws + 84 * MB);
    unsigned short* wAt_h = (unsigned short*)(ws + 92 * MB);   // [768,512]
    unsigned short* wAt_l = (unsigned short*)(ws + 93 * MB);
    unsigned short* wost_h = (unsigned short*)(ws + 94 * MB);  // [256,1024]
    unsigned short* wost_l = (unsigned short*)(ws + 95 * MB);
    unsigned short* wot_h  = (unsigned short*)(ws + 96 * MB);  // [256,768]
    unsigned short* wot_l  = (unsigned short*)(ws + 97 * MB);

    const int* srcA = ei;          // edge_index[0]
    const int* dstA = ei + NEDGE;  // edge_index[1]

    // prep (splits + weight transforms + cnt zero), independent of CSR
    k_prep<<<9057, 256, 0, stream>>>(x_self, x_neighbor, w_in_self, w_out_self, w_out,
                                     gw1, gw2, gb1, xsh, xsl, xnh, xnl,
                                     wAt_h, wAt_l, wost_h, wost_l, wot_h, wot_l, bc, cnt);

    // CSR build
    k_count<<<NEDGE / 256, 256, 0, stream>>>(dstA, cnt, NEDGE);
    k_scan<<<1, 256, 0, stream>>>(cnt, row_start, cursor, dinv);
    k_fill_csr2<<<NEDGE / 256, 256, 0, stream>>>(srcA, dstA, cursor, dinv, slist, wlist, NEDGE);

    // fused GEMM: xs @ [Win | Wc] -> l1 (relu, split) + hc (fp32)
    k_gemm128_A<<<768, 256, 0, stream>>>(
        xsh, xsl, wAt_h, wAt_l, b_in_self, l1h, l1l, hc);

    // double aggregation: t1 = S hc ; g2 = S t1 + svec*bc + gb2 (split, svec inline)
    k_agg2<0><<<NNODE, 256, 0, stream>>>(row_start, slist, wlist, dinv, hc,
                                         nullptr, nullptr, t1, nullptr, nullptr);
    k_agg2<1><<<NNODE, 256, 0, stream>>>(row_start, slist, wlist, dinv, t1,
                                         bc, gb2, nullptr, g2h, g2l);

    // z = [ [xs|l1]@wost + b_os , [xn|g2]@wot + b_o ]  (split into zhi/zlo)
    k_gemm128_Z<<<512, 256, 0, stream>>>(
        xsh, xsl, l1h, l1l, xnh, xnl, g2h, g2l,
        wost_h, wost_l, wot_h, wot_l, b_out_self, b_out, zhi, zlo);

    // out = sigmoid(z z^T), 128x256 rect tiles
    k_zzt_rect<<<1056, 256, 0, stream>>>(zhi, zlo, out);
}

// Round 11
// 396.260 us; speedup vs baseline: 1.0369x; 1.0369x over previous
//
#include <hip/hip_runtime.h>
#include <cstdint>
#include <cstddef>

#define NNODE 8192
#define NEDGE 262144

typedef __attribute__((ext_vector_type(8))) short bf16x8;
typedef __attribute__((ext_vector_type(4))) float f32x4;

// ---------------- bf16 split helpers ----------------
__device__ __forceinline__ unsigned short f2bf_rn(float x) {
    unsigned u = __float_as_uint(x);
    u = (u + 0x7FFFu + ((u >> 16) & 1u)) >> 16;
    return (unsigned short)u;
}
__device__ __forceinline__ float bf2f(unsigned short h) {
    return __uint_as_float(((unsigned)h) << 16);
}

__device__ __forceinline__ void gload16(const char* gp, char* lp) {
    __builtin_amdgcn_global_load_lds((const __attribute__((address_space(1))) void*)gp,
                                     (__attribute__((address_space(3))) void*)lp, 16, 0, 0);
}

// ---------------- CSR kernels ----------------

__global__ void k_count(const int* __restrict__ dst, int* __restrict__ cnt, int n) {
    int i = blockIdx.x * blockDim.x + threadIdx.x;
    if (i < n) atomicAdd(&cnt[dst[i]], 1);
}

__global__ __launch_bounds__(256) void k_scan(const int* __restrict__ cnt,
                                              int* __restrict__ row_start,
                                              int* __restrict__ cursor,
                                              float* __restrict__ dinv) {
    __shared__ int part[256];
    const int tid = threadIdx.x;
    const int PER = NNODE / 256;  // 32
    const int base = tid * PER;
    int loc[PER];
    int sum = 0;
#pragma unroll
    for (int i = 0; i < PER; ++i) { loc[i] = cnt[base + i]; sum += loc[i]; }
    part[tid] = sum;
    __syncthreads();
    if (tid == 0) {
        int r = 0;
        for (int i = 0; i < 256; ++i) { int t = part[i]; part[i] = r; r += t; }
    }
    __syncthreads();
    int run = part[tid];
#pragma unroll
    for (int i = 0; i < PER; ++i) {
        row_start[base + i] = run;
        cursor[base + i] = run;
        dinv[base + i] = rsqrtf((float)loc[i] + 1.0f);  // deg = in-degree + self loop
        run += loc[i];
    }
    if (tid == 255) row_start[NNODE] = run;
}

__global__ void k_fill_csr2(const int* __restrict__ src, const int* __restrict__ dst,
                            int* __restrict__ cursor, const float* __restrict__ dinv,
                            int* __restrict__ slist, float* __restrict__ wlist, int n) {
    int e = blockIdx.x * blockDim.x + threadIdx.x;
    if (e < n) {
        int d = dst[e];
        int s = src[e];
        int pos = atomicAdd(&cursor[d], 1);
        slist[pos] = s;
        wlist[pos] = dinv[s] * dinv[d];
    }
}

// ---------------- mega prep kernel (also zeroes cnt) ----------------
__device__ __forceinline__ void split_wt_tile(const float* __restrict__ W, int K, int N,
                                              int k0, int n0,
                                              unsigned short* __restrict__ Oh,
                                              unsigned short* __restrict__ Ol,
                                              float (*t)[33]) {
    const int c = threadIdx.x & 31, r8 = threadIdx.x >> 5;
#pragma unroll
    for (int i = 0; i < 4; ++i) {
        int r = r8 + i * 8;
        t[r][c] = W[(size_t)(k0 + r) * N + n0 + c];
    }
    __syncthreads();
#pragma unroll
    for (int i = 0; i < 4; ++i) {
        int r = r8 + i * 8;
        float x = t[c][r];
        unsigned short h = f2bf_rn(x);
        Oh[(size_t)(n0 + r) * K + k0 + c] = h;
        Ol[(size_t)(n0 + r) * K + k0 + c] = f2bf_rn(x - bf2f(h));
    }
}

__global__ __launch_bounds__(256) void k_prep(
    const float* __restrict__ x_self, const float* __restrict__ x_neighbor,
    const float* __restrict__ w_in_self, const float* __restrict__ w_out_self,
    const float* __restrict__ w_out, const float* __restrict__ gw1,
    const float* __restrict__ gw2, const float* __restrict__ gb1,
    unsigned short* __restrict__ xsh, unsigned short* __restrict__ xsl,
    unsigned short* __restrict__ xnh, unsigned short* __restrict__ xnl,
    unsigned short* __restrict__ wAt_h, unsigned short* __restrict__ wAt_l,
    unsigned short* __restrict__ wost_h, unsigned short* __restrict__ wost_l,
    unsigned short* __restrict__ wot_h, unsigned short* __restrict__ wot_l,
    float* __restrict__ bc, int* __restrict__ cnt) {
    __shared__ float t[32][33];
    const int b = blockIdx.x;
    const int tid = threadIdx.x;
    if (b < 8192) {  // splits
        const float* src = (b < 4096) ? x_self : x_neighbor;
        unsigned short* oh = (b < 4096) ? xsh : xnh;
        unsigned short* ol = (b < 4096) ? xsl : xnl;
        const int i = (b & 4095) * 256 + tid;
        float4 v = ((const float4*)src)[i];
        float x[4] = {v.x, v.y, v.z, v.w};
        unsigned short h[4], l[4];
#pragma unroll
        for (int j = 0; j < 4; ++j) {
            h[j] = f2bf_rn(x[j]);
            l[j] = f2bf_rn(x[j] - bf2f(h[j]));
        }
        ((ushort4*)oh)[i] = make_ushort4(h[0], h[1], h[2], h[3]);
        ((ushort4*)ol)[i] = make_ushort4(l[0], l[1], l[2], l[3]);
    } else if (b < 8448) {
        const int b2 = b - 8192;
        split_wt_tile(w_in_self, 512, 512, (b2 & 15) * 32, (b2 >> 4) * 32, wAt_h, wAt_l, t);
    } else if (b < 8576) {  // Wc = gw1 @ gw2 on the fly
        const int b3 = b - 8448;
        const int k0 = (b3 & 15) * 32, n0 = (b3 >> 4) * 32;
        const int nloc = tid & 31, kg = tid >> 5;
        float a[4] = {0.f, 0.f, 0.f, 0.f};
        for (int c = 0; c < 512; ++c) {
            float g2v = gw2[(size_t)c * 256 + n0 + nloc];
#pragma unroll
            for (int i = 0; i < 4; ++i)
                a[i] += gw1[(size_t)(k0 + kg * 4 + i) * 512 + c] * g2v;
        }
#pragma unroll
        for (int i = 0; i < 4; ++i) {
            unsigned short hh = f2bf_rn(a[i]);
            wAt_h[(size_t)(512 + n0 + nloc) * 512 + k0 + kg * 4 + i] = hh;
            wAt_l[(size_t)(512 + n0 + nloc) * 512 + k0 + kg * 4 + i] = f2bf_rn(a[i] - bf2f(hh));
        }
    } else if (b < 8832) {
        const int b4 = b - 8576;
        split_wt_tile(w_out_self, 1024, 256, (b4 & 31) * 32, (b4 >> 5) * 32, wost_h, wost_l, t);
    } else if (b < 9024) {
        const int b5 = b - 8832;
        split_wt_tile(w_out, 768, 256, (b5 % 24) * 32, (b5 / 24) * 32, wot_h, wot_l, t);
    } else if (b == 9024) {
        float a = 0.0f;
        for (int c = 0; c < 512; ++c) a += gb1[c] * gw2[(size_t)c * 256 + tid];
        bc[tid] = a;
    } else {  // zero cnt: blocks 9025..9056
        cnt[(b - 9025) * 256 + tid] = 0;
    }
}

// ---------------- shared GEMM pieces (128x64 tile, 4 waves, BK=32) ----------------
__device__ __forceinline__ void stage_g(char* buf,
                                        const char* aH, const char* aL, size_t strA,
                                        const char* bH, const char* bL, size_t strB,
                                        int rloc, int w) {
#pragma unroll
    for (int i = 0; i < 2; ++i) {
        const size_t r = (size_t)(rloc + i * 64);
        char* lp = buf + i * 4096 + w * 1024;
        gload16(aH + r * strA, lp);
        gload16(aL + r * strA, lp + 8192);
    }
    gload16(bH + (size_t)rloc * strB, buf + 16384 + w * 1024);
    gload16(bL + (size_t)rloc * strB, buf + 20480 + w * 1024);
}

__device__ __forceinline__ void core_2x4(const char* cur, int w, int sread, int lane,
                                         f32x4 acc[2][4]) {
    bf16x8 ah[2], al[2], bh[4], bl[4];
#pragma unroll
    for (int m = 0; m < 2; ++m) {
        const int row = w * 32 + m * 16 + (lane & 15);
        ah[m] = *(const bf16x8*)(cur + row * 64 + sread);
        al[m] = *(const bf16x8*)(cur + 8192 + row * 64 + sread);
    }
#pragma unroll
    for (int n = 0; n < 4; ++n) {
        const int row = n * 16 + (lane & 15);
        bh[n] = *(const bf16x8*)(cur + 16384 + row * 64 + sread);
        bl[n] = *(const bf16x8*)(cur + 20480 + row * 64 + sread);
    }
#pragma unroll
    for (int m = 0; m < 2; ++m)
#pragma unroll
        for (int n = 0; n < 4; ++n) {
            acc[m][n] = __builtin_amdgcn_mfma_f32_16x16x32_bf16(ah[m], bh[n], acc[m][n], 0, 0, 0);
            acc[m][n] = __builtin_amdgcn_mfma_f32_16x16x32_bf16(ah[m], bl[n], acc[m][n], 0, 0, 0);
            acc[m][n] = __builtin_amdgcn_mfma_f32_16x16x32_bf16(al[m], bh[n], acc[m][n], 0, 0, 0);
        }
}

// ---------------- GEMM-A: xs @ [Win | Wc] -> l1 (relu,split) + hc (fp32) ----------------
// 1D grid 768 = 8 x 96, XCD-chunked. Counted-vmcnt depth-2 pipeline.
__global__ __launch_bounds__(256) void k_gemm128_A(
    const unsigned short* __restrict__ xsh, const unsigned short* __restrict__ xsl,
    const unsigned short* __restrict__ wAt_h, const unsigned short* __restrict__ wAt_l,
    const float* __restrict__ bias,
    unsigned short* __restrict__ l1h, unsigned short* __restrict__ l1l,
    float* __restrict__ hc) {
    __shared__ __align__(16) char smem[49152];
    const int tid = threadIdx.x, lane = tid & 63, w = tid >> 6;
    const int t0 = blockIdx.x;
    const int s = (t0 & 7) * 96 + (t0 >> 3);
    const int bm = (s / 12) * 128, bn = (s % 12) * 64;
    const int rloc = w * 16 + (lane >> 2);
    const int swz_src = ((lane & 3) ^ ((lane >> 3) & 3)) * 16;
    const int sread = ((lane >> 4) ^ ((lane >> 1) & 3)) * 16;
    const char* Ah = (const char*)xsh + (size_t)bm * 1024 + swz_src;
    const char* Al = (const char*)xsl + (size_t)bm * 1024 + swz_src;
    const char* Bh = (const char*)wAt_h + (size_t)bn * 1024 + swz_src;
    const char* Bl = (const char*)wAt_l + (size_t)bn * 1024 + swz_src;

    f32x4 acc[2][4] = {};
    stage_g(smem,         Ah,      Al,      1024, Bh,      Bl,      1024, rloc, w);
    stage_g(smem + 24576, Ah + 64, Al + 64, 1024, Bh + 64, Bl + 64, 1024, rloc, w);
    for (int ks = 0; ks < 16; ++ks) {
        if (ks < 15) asm volatile("s_waitcnt vmcnt(6)" ::: "memory");
        else         asm volatile("s_waitcnt vmcnt(0)" ::: "memory");
        __builtin_amdgcn_s_barrier();
        __builtin_amdgcn_sched_barrier(0);
        core_2x4(smem + (ks & 1) * 24576, w, sread, lane, acc);
        __builtin_amdgcn_sched_barrier(0);
        __builtin_amdgcn_s_barrier();
        if (ks < 14) {
            const int kb = (ks + 2) * 64;
            stage_g(smem + (ks & 1) * 24576, Ah + kb, Al + kb, 1024,
                    Bh + kb, Bl + kb, 1024, rloc, w);
        }
    }

    const int rj = (lane >> 4) * 4, cc = lane & 15;
#pragma unroll
    for (int m = 0; m < 2; ++m) {
#pragma unroll
        for (int n = 0; n < 4; ++n) {
            const int col = bn + n * 16 + cc;
#pragma unroll
            for (int j = 0; j < 4; ++j) {
                const int row = bm + w * 32 + m * 16 + rj + j;
                float x = acc[m][n][j];
                if (col < 512) {
                    x += bias[col];
                    x = fmaxf(x, 0.0f);
                    unsigned short h = f2bf_rn(x);
                    l1h[(size_t)row * 512 + col] = h;
                    l1l[(size_t)row * 512 + col] = f2bf_rn(x - bf2f(h));
                } else {
                    hc[(size_t)row * 256 + (col - 512)] = x;
                }
            }
        }
    }
}

// ---------------- GEMM-Z: z halves, concat-K. 1D grid 512 = 8 x 64, counted-vmcnt ----------------
// half = s & 1 so each XCD gets an even mix of K=1024 and K=768 blocks.
__global__ __launch_bounds__(256) void k_gemm128_Z(
    const unsigned short* __restrict__ xsh, const unsigned short* __restrict__ xsl,
    const unsigned short* __restrict__ l1h, const unsigned short* __restrict__ l1l,
    const unsigned short* __restrict__ xnh, const unsigned short* __restrict__ xnl,
    const unsigned short* __restrict__ g2h, const unsigned short* __restrict__ g2l,
    const unsigned short* __restrict__ wost_h, const unsigned short* __restrict__ wost_l,
    const unsigned short* __restrict__ wot_h, const unsigned short* __restrict__ wot_l,
    const float* __restrict__ b_out_self, const float* __restrict__ b_out,
    unsigned short* __restrict__ zhi, unsigned short* __restrict__ zlo) {
    __shared__ __align__(16) char smem[49152];
    const int t0 = blockIdx.x;
    const int s = (t0 & 7) * 64 + (t0 >> 3);
    const int half = s & 1;
    const int rem = s >> 1;
    const int bn = (rem & 3) * 64;
    const int bm = (rem >> 2) * 128;
    const int tid = threadIdx.x, lane = tid & 63, w = tid >> 6;
    const int rloc = w * 16 + (lane >> 2);
    const int swz_src = ((lane & 3) ^ ((lane >> 3) & 3)) * 16;
    const int sread = ((lane >> 4) ^ ((lane >> 1) & 3)) * 16;

    const unsigned short *A1h, *A1l, *A2h, *A2l, *Wh, *Wl;
    const float* bias;
    int Ktot;
    size_t strA2, strB;
    if (half == 0) {
        A1h = xsh; A1l = xsl; A2h = l1h; A2l = l1l; strA2 = 1024;
        Wh = wost_h; Wl = wost_l; strB = 2048; Ktot = 1024; bias = b_out_self;
    } else {
        A1h = xnh; A1l = xnl; A2h = g2h; A2l = g2l; strA2 = 512;
        Wh = wot_h; Wl = wot_l; strB = 1536; Ktot = 768; bias = b_out;
    }
    const int nsteps = Ktot / 32;
    const char* Bh = (const char*)Wh + (size_t)bn * strB + swz_src;
    const char* Bl = (const char*)Wl + (size_t)bn * strB + swz_src;

    auto asrc = [&](int k0, const char*& sh, const char*& sl, size_t& st) {
        if (k0 < 512) {
            sh = (const char*)A1h + (size_t)bm * 1024 + (size_t)k0 * 2 + swz_src;
            sl = (const char*)A1l + (size_t)bm * 1024 + (size_t)k0 * 2 + swz_src;
            st = 1024;
        } else {
            sh = (const char*)A2h + (size_t)bm * strA2 + (size_t)(k0 - 512) * 2 + swz_src;
            sl = (const char*)A2l + (size_t)bm * strA2 + (size_t)(k0 - 512) * 2 + swz_src;
            st = strA2;
        }
    };

    f32x4 acc[2][4] = {};
    {
        const char *sh, *sl; size_t st;
        asrc(0, sh, sl, st);
        stage_g(smem, sh, sl, st, Bh, Bl, strB, rloc, w);
        asrc(32, sh, sl, st);
        stage_g(smem + 24576, sh, sl, st, Bh + 64, Bl + 64, strB, rloc, w);
    }
    for (int ks = 0; ks < nsteps; ++ks) {
        if (ks < nsteps - 1) asm volatile("s_waitcnt vmcnt(6)" ::: "memory");
        else                 asm volatile("s_waitcnt vmcnt(0)" ::: "memory");
        __builtin_amdgcn_s_barrier();
        __builtin_amdgcn_sched_barrier(0);
        core_2x4(smem + (ks & 1) * 24576, w, sread, lane, acc);
        __builtin_amdgcn_sched_barrier(0);
        __builtin_amdgcn_s_barrier();
        if (ks + 2 < nsteps) {
            const char *sh, *sl; size_t st;
            asrc((ks + 2) * 32, sh, sl, st);
            stage_g(smem + (ks & 1) * 24576, sh, sl, st,
                    Bh + (size_t)(ks + 2) * 64, Bl + (size_t)(ks + 2) * 64, strB, rloc, w);
        }
    }

    const int rj = (lane >> 4) * 4, cc = lane & 15;
    const int zoff = half * 256;
#pragma unroll
    for (int m = 0; m < 2; ++m) {
#pragma unroll
        for (int n = 0; n < 4; ++n) {
            const int col = bn + n * 16 + cc;  // 0..255 within half
            const float bv = bias[col];
#pragma unroll
            for (int j = 0; j < 4; ++j) {
                const int row = bm + w * 32 + m * 16 + rj + j;
                float x = acc[m][n][j] + bv;
                unsigned short h = f2bf_rn(x);
                zhi[(size_t)row * 512 + zoff + col] = h;
                zlo[(size_t)row * 512 + zoff + col] = f2bf_rn(x - bf2f(h));
            }
        }
    }
}

// ---------------- GCN aggregation, unroll-8 gathers ----------------
template <int MODE>
__global__ __launch_bounds__(256) void k_agg2(
    const int* __restrict__ row_start, const int* __restrict__ slist,
    const float* __restrict__ wlist, const float* __restrict__ dinv,
    const float* __restrict__ h,
    const float* __restrict__ bc, const float* __restrict__ b2,
    float* __restrict__ outf,
    unsigned short* __restrict__ oh, unsigned short* __restrict__ ol) {
    const int n = blockIdx.x;
    const int c = threadIdx.x;
    const float di = dinv[n];
    float acc = di * di * h[(size_t)n * 256 + c];
    float sv = di * di;
    const int e0 = row_start[n], e1 = row_start[n + 1];
    int j = e0;
    for (; j + 8 <= e1; j += 8) {
        int ss[8];
        float ww[8], vv[8];
#pragma unroll
        for (int u = 0; u < 8; ++u) { ss[u] = slist[j + u]; ww[u] = wlist[j + u]; }
#pragma unroll
        for (int u = 0; u < 8; ++u) vv[u] = h[(size_t)ss[u] * 256 + c];
#pragma unroll
        for (int u = 0; u < 8; ++u) {
            acc += ww[u] * vv[u];
            if (MODE) sv += ww[u];
        }
    }
    for (; j < e1; ++j) {
        const float wv = wlist[j];
        acc += wv * h[(size_t)slist[j] * 256 + c];
        if (MODE) sv += wv;
    }
    if (MODE == 0) {
        outf[(size_t)n * 256 + c] = acc;
    } else {
        float x = acc + sv * bc[c] + b2[c];
        unsigned short hb = f2bf_rn(x);
        oh[(size_t)n * 256 + c] = hb;
        ol[(size_t)n * 256 + c] = f2bf_rn(x - bf2f(hb));
    }
}

// ---------------- out = sigmoid(Z Z^T), 256x128 rect tiles, 8 waves, counted-vmcnt ----------------
// Tiles (I,J): rows I*256..+255, cols J*128..+127, selected for J <= 2I+1 (1056 tiles;
// p = I^2+I+J). Direct tile + unconditional mirror covers the full symmetric matrix
// (overlaps write identical values). 512 threads, wave tile 64x64 (acc[4][4]) -- the
// per-wave pattern of the proven 128^2 config. LDS/buf 48KB: Ah 16K | Al 16K | Bh 8K | Bl 8K.
__global__ __launch_bounds__(512, 2) void k_zzt_rect(const unsigned short* __restrict__ zhi,
                                                     const unsigned short* __restrict__ zlo,
                                                     float* __restrict__ out) {
    __shared__ __align__(16) char smem[98304];  // 2 x 48KB
    const int tid = threadIdx.x;
    const int lane = tid & 63;
    const int w = tid >> 6;             // 0..7
    const int wr = w >> 1, wc = w & 1;  // wave tile: rows wr*64, cols wc*64

    // XCD swizzle (1056 = 8 x 132, bijective), then decode p = I^2+I+J
    const int t0 = blockIdx.x;
    const int p = (t0 & 7) * 132 + (t0 >> 3);
    int I = (int)((sqrtf(4.0f * (float)p + 1.0f) - 1.0f) * 0.5f);
    while ((I + 1) * (I + 2) <= p) ++I;
    while (I * (I + 1) > p) --I;
    const int J = p - I * (I + 1);

    const char* pp[4];
    pp[0] = (const char*)zhi + (size_t)(I * 256) * 1024;  // A hi (256 rows)
    pp[1] = (const char*)zlo + (size_t)(I * 256) * 1024;  // A lo
    pp[2] = (const char*)zhi + (size_t)(J * 128) * 1024;  // B hi (128 rows)
    pp[3] = (const char*)zlo + (size_t)(J * 128) * 1024;  // B lo

    const int swz_src = ((lane & 3) ^ ((lane >> 3) & 3)) * 16;
    const int sread = ((lane >> 4) ^ ((lane >> 1) & 3)) * 16;

    // stage one K32 step: 48 chunks of 16 rows (A: 16 hi + 16 lo; B: 8 hi + 8 lo);
    // wave w owns chunks w*6..w*6+5 -> 6 gload16 per lane (same count as stage_g).
    auto STAGE = [&](int buf, int kt) {
        const int kb = kt * 64;
        char* base = smem + buf * 49152;
#pragma unroll
        for (int jj = 0; jj < 6; ++jj) {
            const int c = w * 6 + jj;
            const char* src;
            char* dst;
            if (c < 32) {  // A chunks: q = hi/lo, ci = 0..15
                const int q = c >> 4, ci = c & 15;
                dst = base + q * 16384 + ci * 1024;
                src = pp[q] + (size_t)(ci * 16 + (lane >> 2)) * 1024 + kb + swz_src;
            } else {       // B chunks: ci = 0..7 per dtype
                const int c2 = c - 32;
                const int q = 2 + (c2 >> 3), ci = c2 & 7;
                dst = base + 32768 + (c2 >> 3) * 8192 + ci * 1024;
                src = pp[q] + (size_t)(ci * 16 + (lane >> 2)) * 1024 + kb + swz_src;
            }
            gload16(src, dst);
        }
    };

    f32x4 acc[4][4] = {};

    STAGE(0, 0);
    STAGE(1, 1);

    for (int ks = 0; ks < 16; ++ks) {
        if (ks < 15) asm volatile("s_waitcnt vmcnt(6)" ::: "memory");
        else         asm volatile("s_waitcnt vmcnt(0)" ::: "memory");
        __builtin_amdgcn_s_barrier();
        __builtin_amdgcn_sched_barrier(0);
        const char* cur = smem + (ks & 1) * 49152;

        bf16x8 ah[4], al[4], bh[4], bl[4];
#pragma unroll
        for (int m = 0; m < 4; ++m) {
            const int row = wr * 64 + m * 16 + (lane & 15);
            ah[m] = *(const bf16x8*)(cur + row * 64 + sread);
            al[m] = *(const bf16x8*)(cur + 16384 + row * 64 + sread);
        }
#pragma unroll
        for (int n = 0; n < 4; ++n) {
            const int cr = wc * 64 + n * 16 + (lane & 15);
            bh[n] = *(const bf16x8*)(cur + 32768 + cr * 64 + sread);
            bl[n] = *(const bf16x8*)(cur + 40960 + cr * 64 + sread);
        }
        __builtin_amdgcn_s_setprio(1);
#pragma unroll
        for (int m = 0; m < 4; ++m)
#pragma unroll
            for (int n = 0; n < 4; ++n) {
                acc[m][n] = __builtin_amdgcn_mfma_f32_16x16x32_bf16(ah[m], bh[n], acc[m][n], 0, 0, 0);
                acc[m][n] = __builtin_amdgcn_mfma_f32_16x16x32_bf16(ah[m], bl[n], acc[m][n], 0, 0, 0);
                acc[m][n] = __builtin_amdgcn_mfma_f32_16x16x32_bf16(al[m], bh[n], acc[m][n], 0, 0, 0);
            }
        __builtin_amdgcn_s_setprio(0);
        __builtin_amdgcn_sched_barrier(0);
        __builtin_amdgcn_s_barrier();
        if (ks < 14) STAGE(ks & 1, ks + 2);
    }

    // epilogue: sigmoid once; direct tile + unconditional mirror (NT stores)
    const int rj = (lane >> 4) * 4;
    const int cc = lane & 15;
#pragma unroll
    for (int m = 0; m < 4; ++m) {
#pragma unroll
        for (int n = 0; n < 4; ++n) {
            float s[4];
#pragma unroll
            for (int j = 0; j < 4; ++j)
                s[j] = 1.0f / (1.0f + __expf(-acc[m][n][j]));
            const int gr0 = I * 256 + wr * 64 + m * 16 + rj;
            const int gc  = J * 128 + wc * 64 + n * 16 + cc;
#pragma unroll
            for (int j = 0; j < 4; ++j)
                __builtin_nontemporal_store(s[j], out + (size_t)(gr0 + j) * NNODE + gc);
            f32x4 v = {s[0], s[1], s[2], s[3]};
            __builtin_nontemporal_store(v, (f32x4*)(out + (size_t)gc * NNODE + gr0));
        }
    }
}

// ---------------- launch ----------------
extern "C" void kernel_launch(void* const* d_in, const int* in_sizes, int n_in,
                              void* d_out, int out_size, void* d_ws, size_t ws_size,
                              hipStream_t stream) {
    const float* x_self     = (const float*)d_in[0];
    const float* x_neighbor = (const float*)d_in[1];
    const int*   ei         = (const int*)d_in[2];
    const float* w_in_self  = (const float*)d_in[3];
    const float* b_in_self  = (const float*)d_in[4];
    const float* w_out_self = (const float*)d_in[5];
    const float* b_out_self = (const float*)d_in[6];
    const float* gw1        = (const float*)d_in[7];
    const float* gb1        = (const float*)d_in[8];
    const float* gw2        = (const float*)d_in[9];
    const float* gb2        = (const float*)d_in[10];
    const float* w_out      = (const float*)d_in[11];
    const float* b_out      = (const float*)d_in[12];
    float* out = (float*)d_out;

    char* ws = (char*)d_ws;
    const size_t MB = 1024 * 1024;
    const size_t KB = 1024;
    int*   cnt       = (int*)(ws + 0);
    int*   row_start = (int*)(ws + 32 * KB);
    int*   cursor    = (int*)(ws + 96 * KB);
    float* dinv      = (float*)(ws + 128 * KB);
    float* bc        = (float*)(ws + 192 * KB);
    int*   slist     = (int*)(ws + 2 * MB);
    float* wlist     = (float*)(ws + 3 * MB);
    unsigned short* xsh = (unsigned short*)(ws + 4 * MB);
    unsigned short* xsl = (unsigned short*)(ws + 12 * MB);
    unsigned short* xnh = (unsigned short*)(ws + 20 * MB);
    unsigned short* xnl = (unsigned short*)(ws + 28 * MB);
    unsigned short* l1h = (unsigned short*)(ws + 36 * MB);
    unsigned short* l1l = (unsigned short*)(ws + 44 * MB);
    float*          hc  = (float*)(ws + 52 * MB);   // 8 MB fp32 [8192,256]
    float*          t1  = (float*)(ws + 60 * MB);   // 8 MB fp32
    unsigned short* g2h = (unsigned short*)(ws + 68 * MB);
    unsigned short* g2l = (unsigned short*)(ws + 72 * MB);
    unsigned short* zhi = (unsigned short*)(ws + 76 * MB);
    unsigned short* zlo = (unsigned short*)(ws + 84 * MB);
    unsigned short* wAt_h = (unsigned short*)(ws + 92 * MB);   // [768,512]
    unsigned short* wAt_l = (unsigned short*)(ws + 93 * MB);
    unsigned short* wost_h = (unsigned short*)(ws + 94 * MB);  // [256,1024]
    unsigned short* wost_l = (unsigned short*)(ws + 95 * MB);
    unsigned short* wot_h  = (unsigned short*)(ws + 96 * MB);  // [256,768]
    unsigned short* wot_l  = (unsigned short*)(ws + 97 * MB);

    const int* srcA = ei;          // edge_index[0]
    const int* dstA = ei + NEDGE;  // edge_index[1]

    // prep (splits + weight transforms + cnt zero), independent of CSR
    k_prep<<<9057, 256, 0, stream>>>(x_self, x_neighbor, w_in_self, w_out_self, w_out,
                                     gw1, gw2, gb1, xsh, xsl, xnh, xnl,
                                     wAt_h, wAt_l, wost_h, wost_l, wot_h, wot_l, bc, cnt);

    // CSR build
    k_count<<<NEDGE / 256, 256, 0, stream>>>(dstA, cnt, NEDGE);
    k_scan<<<1, 256, 0, stream>>>(cnt, row_start, cursor, dinv);
    k_fill_csr2<<<NEDGE / 256, 256, 0, stream>>>(srcA, dstA, cursor, dinv, slist, wlist, NEDGE);

    // fused GEMM: xs @ [Win | Wc] -> l1 (relu, split) + hc (fp32)
    k_gemm128_A<<<768, 256, 0, stream>>>(
        xsh, xsl, wAt_h, wAt_l, b_in_self, l1h, l1l, hc);

    // double aggregation: t1 = S hc ; g2 = S t1 + svec*bc + gb2 (split, svec inline)
    k_agg2<0><<<NNODE, 256, 0, stream>>>(row_start, slist, wlist, dinv, hc,
                                         nullptr, nullptr, t1, nullptr, nullptr);
    k_agg2<1><<<NNODE, 256, 0, stream>>>(row_start, slist, wlist, dinv, t1,
                                         bc, gb2, nullptr, g2h, g2l);

    // z = [ [xs|l1]@wost + b_os , [xn|g2]@wot + b_o ]  (split into zhi/zlo)
    k_gemm128_Z<<<512, 256, 0, stream>>>(
        xsh, xsl, l1h, l1l, xnh, xnl, g2h, g2l,
        wost_h, wost_l, wot_h, wot_l, b_out_self, b_out, zhi, zlo);

    // out = sigmoid(z z^T), 256x128 rect tiles, 8 waves
    k_zzt_rect<<<1056, 512, 0, stream>>>(zhi, zlo, out);
}

// Round 12
// 354.233 us; speedup vs baseline: 1.1599x; 1.1186x over previous
//
#include <hip/hip_runtime.h>
#include <cstdint>
#include <cstddef>

#define NNODE 8192
#define NEDGE 262144

typedef __attribute__((ext_vector_type(8))) short bf16x8;
typedef __attribute__((ext_vector_type(4))) float f32x4;

// ---------------- bf16 split helpers ----------------
__device__ __forceinline__ unsigned short f2bf_rn(float x) {
    unsigned u = __float_as_uint(x);
    u = (u + 0x7FFFu + ((u >> 16) & 1u)) >> 16;
    return (unsigned short)u;
}
__device__ __forceinline__ float bf2f(unsigned short h) {
    return __uint_as_float(((unsigned)h) << 16);
}

__device__ __forceinline__ void gload16(const char* gp, char* lp) {
    __builtin_amdgcn_global_load_lds((const __attribute__((address_space(1))) void*)gp,
                                     (__attribute__((address_space(3))) void*)lp, 16, 0, 0);
}

// ---------------- CSR kernels ----------------

__global__ void k_count(const int* __restrict__ dst, int* __restrict__ cnt, int n) {
    int i = blockIdx.x * blockDim.x + threadIdx.x;
    if (i < n) atomicAdd(&cnt[dst[i]], 1);
}

__global__ __launch_bounds__(256) void k_scan(const int* __restrict__ cnt,
                                              int* __restrict__ row_start,
                                              int* __restrict__ cursor,
                                              float* __restrict__ dinv) {
    __shared__ int part[256];
    const int tid = threadIdx.x;
    const int PER = NNODE / 256;  // 32
    const int base = tid * PER;
    int loc[PER];
    int sum = 0;
#pragma unroll
    for (int i = 0; i < PER; ++i) { loc[i] = cnt[base + i]; sum += loc[i]; }
    part[tid] = sum;
    __syncthreads();
    if (tid == 0) {
        int r = 0;
        for (int i = 0; i < 256; ++i) { int t = part[i]; part[i] = r; r += t; }
    }
    __syncthreads();
    int run = part[tid];
#pragma unroll
    for (int i = 0; i < PER; ++i) {
        row_start[base + i] = run;
        cursor[base + i] = run;
        dinv[base + i] = rsqrtf((float)loc[i] + 1.0f);  // deg = in-degree + self loop
        run += loc[i];
    }
    if (tid == 255) row_start[NNODE] = run;
}

__global__ void k_fill_csr2(const int* __restrict__ src, const int* __restrict__ dst,
                            int* __restrict__ cursor, const float* __restrict__ dinv,
                            int* __restrict__ slist, float* __restrict__ wlist, int n) {
    int e = blockIdx.x * blockDim.x + threadIdx.x;
    if (e < n) {
        int d = dst[e];
        int s = src[e];
        int pos = atomicAdd(&cursor[d], 1);
        slist[pos] = s;
        wlist[pos] = dinv[s] * dinv[d];
    }
}

// ---------------- mega prep kernel (also zeroes cnt) ----------------
__device__ __forceinline__ void split_wt_tile(const float* __restrict__ W, int K, int N,
                                              int k0, int n0,
                                              unsigned short* __restrict__ Oh,
                                              unsigned short* __restrict__ Ol,
                                              float (*t)[33]) {
    const int c = threadIdx.x & 31, r8 = threadIdx.x >> 5;
#pragma unroll
    for (int i = 0; i < 4; ++i) {
        int r = r8 + i * 8;
        t[r][c] = W[(size_t)(k0 + r) * N + n0 + c];
    }
    __syncthreads();
#pragma unroll
    for (int i = 0; i < 4; ++i) {
        int r = r8 + i * 8;
        float x = t[c][r];
        unsigned short h = f2bf_rn(x);
        Oh[(size_t)(n0 + r) * K + k0 + c] = h;
        Ol[(size_t)(n0 + r) * K + k0 + c] = f2bf_rn(x - bf2f(h));
    }
}

__global__ __launch_bounds__(256) void k_prep(
    const float* __restrict__ x_self, const float* __restrict__ x_neighbor,
    const float* __restrict__ w_in_self, const float* __restrict__ w_out_self,
    const float* __restrict__ w_out, const float* __restrict__ gw1,
    const float* __restrict__ gw2, const float* __restrict__ gb1,
    unsigned short* __restrict__ xsh, unsigned short* __restrict__ xsl,
    unsigned short* __restrict__ xnh, unsigned short* __restrict__ xnl,
    unsigned short* __restrict__ wAt_h, unsigned short* __restrict__ wAt_l,
    unsigned short* __restrict__ wost_h, unsigned short* __restrict__ wost_l,
    unsigned short* __restrict__ wot_h, unsigned short* __restrict__ wot_l,
    float* __restrict__ bc, int* __restrict__ cnt) {
    __shared__ float t[32][33];
    const int b = blockIdx.x;
    const int tid = threadIdx.x;
    if (b < 8192) {  // splits
        const float* src = (b < 4096) ? x_self : x_neighbor;
        unsigned short* oh = (b < 4096) ? xsh : xnh;
        unsigned short* ol = (b < 4096) ? xsl : xnl;
        const int i = (b & 4095) * 256 + tid;
        float4 v = ((const float4*)src)[i];
        float x[4] = {v.x, v.y, v.z, v.w};
        unsigned short h[4], l[4];
#pragma unroll
        for (int j = 0; j < 4; ++j) {
            h[j] = f2bf_rn(x[j]);
            l[j] = f2bf_rn(x[j] - bf2f(h[j]));
        }
        ((ushort4*)oh)[i] = make_ushort4(h[0], h[1], h[2], h[3]);
        ((ushort4*)ol)[i] = make_ushort4(l[0], l[1], l[2], l[3]);
    } else if (b < 8448) {
        const int b2 = b - 8192;
        split_wt_tile(w_in_self, 512, 512, (b2 & 15) * 32, (b2 >> 4) * 32, wAt_h, wAt_l, t);
    } else if (b < 8576) {  // Wc = gw1 @ gw2 on the fly
        const int b3 = b - 8448;
        const int k0 = (b3 & 15) * 32, n0 = (b3 >> 4) * 32;
        const int nloc = tid & 31, kg = tid >> 5;
        float a[4] = {0.f, 0.f, 0.f, 0.f};
        for (int c = 0; c < 512; ++c) {
            float g2v = gw2[(size_t)c * 256 + n0 + nloc];
#pragma unroll
            for (int i = 0; i < 4; ++i)
                a[i] += gw1[(size_t)(k0 + kg * 4 + i) * 512 + c] * g2v;
        }
#pragma unroll
        for (int i = 0; i < 4; ++i) {
            unsigned short hh = f2bf_rn(a[i]);
            wAt_h[(size_t)(512 + n0 + nloc) * 512 + k0 + kg * 4 + i] = hh;
            wAt_l[(size_t)(512 + n0 + nloc) * 512 + k0 + kg * 4 + i] = f2bf_rn(a[i] - bf2f(hh));
        }
    } else if (b < 8832) {
        const int b4 = b - 8576;
        split_wt_tile(w_out_self, 1024, 256, (b4 & 31) * 32, (b4 >> 5) * 32, wost_h, wost_l, t);
    } else if (b < 9024) {
        const int b5 = b - 8832;
        split_wt_tile(w_out, 768, 256, (b5 % 24) * 32, (b5 / 24) * 32, wot_h, wot_l, t);
    } else if (b == 9024) {
        float a = 0.0f;
        for (int c = 0; c < 512; ++c) a += gb1[c] * gw2[(size_t)c * 256 + tid];
        bc[tid] = a;
    } else {  // zero cnt: blocks 9025..9056
        cnt[(b - 9025) * 256 + tid] = 0;
    }
}

// ---------------- shared GEMM pieces (128x64 tile, 4 waves, BK=32) ----------------
__device__ __forceinline__ void stage_g(char* buf,
                                        const char* aH, const char* aL, size_t strA,
                                        const char* bH, const char* bL, size_t strB,
                                        int rloc, int w) {
#pragma unroll
    for (int i = 0; i < 2; ++i) {
        const size_t r = (size_t)(rloc + i * 64);
        char* lp = buf + i * 4096 + w * 1024;
        gload16(aH + r * strA, lp);
        gload16(aL + r * strA, lp + 8192);
    }
    gload16(bH + (size_t)rloc * strB, buf + 16384 + w * 1024);
    gload16(bL + (size_t)rloc * strB, buf + 20480 + w * 1024);
}

__device__ __forceinline__ void core_2x4(const char* cur, int w, int sread, int lane,
                                         f32x4 acc[2][4]) {
    bf16x8 ah[2], al[2], bh[4], bl[4];
#pragma unroll
    for (int m = 0; m < 2; ++m) {
        const int row = w * 32 + m * 16 + (lane & 15);
        ah[m] = *(const bf16x8*)(cur + row * 64 + sread);
        al[m] = *(const bf16x8*)(cur + 8192 + row * 64 + sread);
    }
#pragma unroll
    for (int n = 0; n < 4; ++n) {
        const int row = n * 16 + (lane & 15);
        bh[n] = *(const bf16x8*)(cur + 16384 + row * 64 + sread);
        bl[n] = *(const bf16x8*)(cur + 20480 + row * 64 + sread);
    }
#pragma unroll
    for (int m = 0; m < 2; ++m)
#pragma unroll
        for (int n = 0; n < 4; ++n) {
            acc[m][n] = __builtin_amdgcn_mfma_f32_16x16x32_bf16(ah[m], bh[n], acc[m][n], 0, 0, 0);
            acc[m][n] = __builtin_amdgcn_mfma_f32_16x16x32_bf16(ah[m], bl[n], acc[m][n], 0, 0, 0);
            acc[m][n] = __builtin_amdgcn_mfma_f32_16x16x32_bf16(al[m], bh[n], acc[m][n], 0, 0, 0);
        }
}

// ---------------- GEMM-A: xs @ [Win | Wc] -> l1 (relu,split) + hc (bf16) ----------------
// 1D grid 768 = 8 x 96, XCD-chunked. Counted-vmcnt depth-2 pipeline.
__global__ __launch_bounds__(256) void k_gemm128_A(
    const unsigned short* __restrict__ xsh, const unsigned short* __restrict__ xsl,
    const unsigned short* __restrict__ wAt_h, const unsigned short* __restrict__ wAt_l,
    const float* __restrict__ bias,
    unsigned short* __restrict__ l1h, unsigned short* __restrict__ l1l,
    unsigned short* __restrict__ hcb) {
    __shared__ __align__(16) char smem[49152];
    const int tid = threadIdx.x, lane = tid & 63, w = tid >> 6;
    const int t0 = blockIdx.x;
    const int s = (t0 & 7) * 96 + (t0 >> 3);
    const int bm = (s / 12) * 128, bn = (s % 12) * 64;
    const int rloc = w * 16 + (lane >> 2);
    const int swz_src = ((lane & 3) ^ ((lane >> 3) & 3)) * 16;
    const int sread = ((lane >> 4) ^ ((lane >> 1) & 3)) * 16;
    const char* Ah = (const char*)xsh + (size_t)bm * 1024 + swz_src;
    const char* Al = (const char*)xsl + (size_t)bm * 1024 + swz_src;
    const char* Bh = (const char*)wAt_h + (size_t)bn * 1024 + swz_src;
    const char* Bl = (const char*)wAt_l + (size_t)bn * 1024 + swz_src;

    f32x4 acc[2][4] = {};
    stage_g(smem,         Ah,      Al,      1024, Bh,      Bl,      1024, rloc, w);
    stage_g(smem + 24576, Ah + 64, Al + 64, 1024, Bh + 64, Bl + 64, 1024, rloc, w);
    for (int ks = 0; ks < 16; ++ks) {
        if (ks < 15) asm volatile("s_waitcnt vmcnt(6)" ::: "memory");
        else         asm volatile("s_waitcnt vmcnt(0)" ::: "memory");
        __builtin_amdgcn_s_barrier();
        __builtin_amdgcn_sched_barrier(0);
        core_2x4(smem + (ks & 1) * 24576, w, sread, lane, acc);
        __builtin_amdgcn_sched_barrier(0);
        __builtin_amdgcn_s_barrier();
        if (ks < 14) {
            const int kb = (ks + 2) * 64;
            stage_g(smem + (ks & 1) * 24576, Ah + kb, Al + kb, 1024,
                    Bh + kb, Bl + kb, 1024, rloc, w);
        }
    }

    const int rj = (lane >> 4) * 4, cc = lane & 15;
#pragma unroll
    for (int m = 0; m < 2; ++m) {
#pragma unroll
        for (int n = 0; n < 4; ++n) {
            const int col = bn + n * 16 + cc;
#pragma unroll
            for (int j = 0; j < 4; ++j) {
                const int row = bm + w * 32 + m * 16 + rj + j;
                float x = acc[m][n][j];
                if (col < 512) {
                    x += bias[col];
                    x = fmaxf(x, 0.0f);
                    unsigned short h = f2bf_rn(x);
                    l1h[(size_t)row * 512 + col] = h;
                    l1l[(size_t)row * 512 + col] = f2bf_rn(x - bf2f(h));
                } else {
                    hcb[(size_t)row * 256 + (col - 512)] = f2bf_rn(x);
                }
            }
        }
    }
}

// ---------------- GEMM-Z: z halves, concat-K. 1D grid 512 = 8 x 64, counted-vmcnt ----------------
__global__ __launch_bounds__(256) void k_gemm128_Z(
    const unsigned short* __restrict__ xsh, const unsigned short* __restrict__ xsl,
    const unsigned short* __restrict__ l1h, const unsigned short* __restrict__ l1l,
    const unsigned short* __restrict__ xnh, const unsigned short* __restrict__ xnl,
    const unsigned short* __restrict__ g2h, const unsigned short* __restrict__ g2l,
    const unsigned short* __restrict__ wost_h, const unsigned short* __restrict__ wost_l,
    const unsigned short* __restrict__ wot_h, const unsigned short* __restrict__ wot_l,
    const float* __restrict__ b_out_self, const float* __restrict__ b_out,
    unsigned short* __restrict__ zhi, unsigned short* __restrict__ zlo) {
    __shared__ __align__(16) char smem[49152];
    const int t0 = blockIdx.x;
    const int s = (t0 & 7) * 64 + (t0 >> 3);
    const int half = s & 1;
    const int rem = s >> 1;
    const int bn = (rem & 3) * 64;
    const int bm = (rem >> 2) * 128;
    const int tid = threadIdx.x, lane = tid & 63, w = tid >> 6;
    const int rloc = w * 16 + (lane >> 2);
    const int swz_src = ((lane & 3) ^ ((lane >> 3) & 3)) * 16;
    const int sread = ((lane >> 4) ^ ((lane >> 1) & 3)) * 16;

    const unsigned short *A1h, *A1l, *A2h, *A2l, *Wh, *Wl;
    const float* bias;
    int Ktot;
    size_t strA2, strB;
    if (half == 0) {
        A1h = xsh; A1l = xsl; A2h = l1h; A2l = l1l; strA2 = 1024;
        Wh = wost_h; Wl = wost_l; strB = 2048; Ktot = 1024; bias = b_out_self;
    } else {
        A1h = xnh; A1l = xnl; A2h = g2h; A2l = g2l; strA2 = 512;
        Wh = wot_h; Wl = wot_l; strB = 1536; Ktot = 768; bias = b_out;
    }
    const int nsteps = Ktot / 32;
    const char* Bh = (const char*)Wh + (size_t)bn * strB + swz_src;
    const char* Bl = (const char*)Wl + (size_t)bn * strB + swz_src;

    auto asrc = [&](int k0, const char*& sh, const char*& sl, size_t& st) {
        if (k0 < 512) {
            sh = (const char*)A1h + (size_t)bm * 1024 + (size_t)k0 * 2 + swz_src;
            sl = (const char*)A1l + (size_t)bm * 1024 + (size_t)k0 * 2 + swz_src;
            st = 1024;
        } else {
            sh = (const char*)A2h + (size_t)bm * strA2 + (size_t)(k0 - 512) * 2 + swz_src;
            sl = (const char*)A2l + (size_t)bm * strA2 + (size_t)(k0 - 512) * 2 + swz_src;
            st = strA2;
        }
    };

    f32x4 acc[2][4] = {};
    {
        const char *sh, *sl; size_t st;
        asrc(0, sh, sl, st);
        stage_g(smem, sh, sl, st, Bh, Bl, strB, rloc, w);
        asrc(32, sh, sl, st);
        stage_g(smem + 24576, sh, sl, st, Bh + 64, Bl + 64, strB, rloc, w);
    }
    for (int ks = 0; ks < nsteps; ++ks) {
        if (ks < nsteps - 1) asm volatile("s_waitcnt vmcnt(6)" ::: "memory");
        else                 asm volatile("s_waitcnt vmcnt(0)" ::: "memory");
        __builtin_amdgcn_s_barrier();
        __builtin_amdgcn_sched_barrier(0);
        core_2x4(smem + (ks & 1) * 24576, w, sread, lane, acc);
        __builtin_amdgcn_sched_barrier(0);
        __builtin_amdgcn_s_barrier();
        if (ks + 2 < nsteps) {
            const char *sh, *sl; size_t st;
            asrc((ks + 2) * 32, sh, sl, st);
            stage_g(smem + (ks & 1) * 24576, sh, sl, st,
                    Bh + (size_t)(ks + 2) * 64, Bl + (size_t)(ks + 2) * 64, strB, rloc, w);
        }
    }

    const int rj = (lane >> 4) * 4, cc = lane & 15;
    const int zoff = half * 256;
#pragma unroll
    for (int m = 0; m < 2; ++m) {
#pragma unroll
        for (int n = 0; n < 4; ++n) {
            const int col = bn + n * 16 + cc;  // 0..255 within half
            const float bv = bias[col];
#pragma unroll
            for (int j = 0; j < 4; ++j) {
                const int row = bm + w * 32 + m * 16 + rj + j;
                float x = acc[m][n][j] + bv;
                unsigned short h = f2bf_rn(x);
                zhi[(size_t)row * 512 + zoff + col] = h;
                zlo[(size_t)row * 512 + zoff + col] = f2bf_rn(x - bf2f(h));
            }
        }
    }
}

// ---------------- GCN aggregation, wave-per-node, bf16 table, ushort4 gathers ----------------
// Block = 256 threads = 4 waves = 4 nodes. Lane handles 4 channels (ushort4 = 8B gather;
// a wave reads one full 512B bf16 row per edge). fp32 accumulate.
// MODE 0: t1 (bf16) = S_hat @ h ;  MODE 1: split-bf16( S_hat @ h + svec*bc + b2 )
template <int MODE>
__global__ __launch_bounds__(256) void k_agg4(
    const int* __restrict__ row_start, const int* __restrict__ slist,
    const float* __restrict__ wlist, const float* __restrict__ dinv,
    const unsigned short* __restrict__ h,
    const float* __restrict__ bc, const float* __restrict__ b2,
    unsigned short* __restrict__ t1,
    unsigned short* __restrict__ oh, unsigned short* __restrict__ ol) {
    const int n = blockIdx.x * 4 + (threadIdx.x >> 6);
    const int lane = threadIdx.x & 63;
    const int c0 = lane * 4;
    const float di = dinv[n];

    ushort4 selfv = ((const ushort4*)(h + (size_t)n * 256))[lane];
    float acc[4];
    acc[0] = di * di * bf2f(selfv.x);
    acc[1] = di * di * bf2f(selfv.y);
    acc[2] = di * di * bf2f(selfv.z);
    acc[3] = di * di * bf2f(selfv.w);
    float sv = di * di;

    const int e0 = row_start[n], e1 = row_start[n + 1];
    int j = e0;
    for (; j + 4 <= e1; j += 4) {
        int ss[4];
        float ww[4];
        ushort4 rv[4];
#pragma unroll
        for (int u = 0; u < 4; ++u) { ss[u] = slist[j + u]; ww[u] = wlist[j + u]; }
#pragma unroll
        for (int u = 0; u < 4; ++u)
            rv[u] = ((const ushort4*)(h + (size_t)ss[u] * 256))[lane];
#pragma unroll
        for (int u = 0; u < 4; ++u) {
            acc[0] += ww[u] * bf2f(rv[u].x);
            acc[1] += ww[u] * bf2f(rv[u].y);
            acc[2] += ww[u] * bf2f(rv[u].z);
            acc[3] += ww[u] * bf2f(rv[u].w);
            if (MODE) sv += ww[u];
        }
    }
    for (; j < e1; ++j) {
        const float wv = wlist[j];
        ushort4 rv = ((const ushort4*)(h + (size_t)slist[j] * 256))[lane];
        acc[0] += wv * bf2f(rv.x);
        acc[1] += wv * bf2f(rv.y);
        acc[2] += wv * bf2f(rv.z);
        acc[3] += wv * bf2f(rv.w);
        if (MODE) sv += wv;
    }

    if (MODE == 0) {
        ushort4 o;
        o.x = f2bf_rn(acc[0]); o.y = f2bf_rn(acc[1]);
        o.z = f2bf_rn(acc[2]); o.w = f2bf_rn(acc[3]);
        ((ushort4*)(t1 + (size_t)n * 256))[lane] = o;
    } else {
        ushort4 vh, vl;
        float x0 = acc[0] + sv * bc[c0 + 0] + b2[c0 + 0];
        float x1 = acc[1] + sv * bc[c0 + 1] + b2[c0 + 1];
        float x2 = acc[2] + sv * bc[c0 + 2] + b2[c0 + 2];
        float x3 = acc[3] + sv * bc[c0 + 3] + b2[c0 + 3];
        vh.x = f2bf_rn(x0); vl.x = f2bf_rn(x0 - bf2f(vh.x));
        vh.y = f2bf_rn(x1); vl.y = f2bf_rn(x1 - bf2f(vh.y));
        vh.z = f2bf_rn(x2); vl.z = f2bf_rn(x2 - bf2f(vh.z));
        vh.w = f2bf_rn(x3); vl.w = f2bf_rn(x3 - bf2f(vh.w));
        ((ushort4*)(oh + (size_t)n * 256))[lane] = vh;
        ((ushort4*)(ol + (size_t)n * 256))[lane] = vl;
    }
}

// ---------------- out = sigmoid(Z Z^T), 128^2, counted-vmcnt depth-2 + NT stores + XCD swz ----------------
__device__ __forceinline__ void zzt_stage(char* buf, const char* s0, const char* s1,
                                          const char* s2, const char* s3,
                                          int rloc, int swz_src, int w, int kbyte) {
    const char* srcs[4] = {s0, s1, s2, s3};
#pragma unroll
    for (int tile = 0; tile < 4; ++tile) {
#pragma unroll
        for (int i = 0; i < 2; ++i) {
            const char* gp = srcs[tile] + (size_t)(rloc + i * 64) * 1024 + kbyte + swz_src;
            char* lp = buf + tile * 8192 + i * 4096 + w * 1024;
            gload16(gp, lp);
        }
    }
}

__global__ __launch_bounds__(256) void k_zzt_mfma(const unsigned short* __restrict__ zhi,
                                                  const unsigned short* __restrict__ zlo,
                                                  float* __restrict__ out) {
    __shared__ __align__(16) char smem[65536];  // 2 x 32KB
    const int tid = threadIdx.x;
    const int lane = tid & 63;
    const int w = tid >> 6;
    const int wr = w >> 1, wc = w & 1;

    // XCD swizzle (2080 = 8 x 260, bijective), then lower-triangular decode (bi >= bj)
    const int t0 = blockIdx.x;
    const int t = (t0 & 7) * 260 + (t0 >> 3);
    int bi = (int)((sqrtf(8.0f * (float)t + 1.0f) - 1.0f) * 0.5f);
    while ((bi + 1) * (bi + 2) / 2 <= t) ++bi;
    while (bi * (bi + 1) / 2 > t) --bi;
    const int bj = t - bi * (bi + 1) / 2;

    const char* s0 = (const char*)zhi + (size_t)(bi * 128) * 1024;
    const char* s1 = (const char*)zlo + (size_t)(bi * 128) * 1024;
    const char* s2 = (const char*)zhi + (size_t)(bj * 128) * 1024;
    const char* s3 = (const char*)zlo + (size_t)(bj * 128) * 1024;

    const int rloc = w * 16 + (lane >> 2);
    const int swz_src = ((lane & 3) ^ ((lane >> 3) & 3)) * 16;
    const int sread = ((lane >> 4) ^ ((lane >> 1) & 3)) * 16;

    f32x4 acc[4][4] = {};

    zzt_stage(smem,         s0, s1, s2, s3, rloc, swz_src, w, 0);
    zzt_stage(smem + 32768, s0, s1, s2, s3, rloc, swz_src, w, 64);

    for (int ks = 0; ks < 16; ++ks) {
        if (ks < 15) asm volatile("s_waitcnt vmcnt(8)" ::: "memory");
        else         asm volatile("s_waitcnt vmcnt(0)" ::: "memory");
        __builtin_amdgcn_s_barrier();
        __builtin_amdgcn_sched_barrier(0);
        const char* cur = smem + (ks & 1) * 32768;

        bf16x8 ah[4], al[4], bh[4], bl[4];
        const char* pa = cur + (wr * 64 + (lane & 15)) * 64 + sread;
        const char* pb = cur + 16384 + (wc * 64 + (lane & 15)) * 64 + sread;
#pragma unroll
        for (int m = 0; m < 4; ++m) {
            ah[m] = *(const bf16x8*)(pa + m * 1024);
            al[m] = *(const bf16x8*)(pa + 8192 + m * 1024);
        }
#pragma unroll
        for (int n = 0; n < 4; ++n) {
            bh[n] = *(const bf16x8*)(pb + n * 1024);
            bl[n] = *(const bf16x8*)(pb + 8192 + n * 1024);
        }
        __builtin_amdgcn_s_setprio(1);
#pragma unroll
        for (int m = 0; m < 4; ++m)
#pragma unroll
            for (int n = 0; n < 4; ++n) {
                acc[m][n] = __builtin_amdgcn_mfma_f32_16x16x32_bf16(ah[m], bh[n], acc[m][n], 0, 0, 0);
                acc[m][n] = __builtin_amdgcn_mfma_f32_16x16x32_bf16(ah[m], bl[n], acc[m][n], 0, 0, 0);
                acc[m][n] = __builtin_amdgcn_mfma_f32_16x16x32_bf16(al[m], bh[n], acc[m][n], 0, 0, 0);
            }
        __builtin_amdgcn_s_setprio(0);
        __builtin_amdgcn_sched_barrier(0);
        __builtin_amdgcn_s_barrier();
        if (ks < 14)
            zzt_stage(smem + (ks & 1) * 32768, s0, s1, s2, s3, rloc, swz_src, w,
                      (ks + 2) * 64);
    }

    const int rj = (lane >> 4) * 4;
    const int cc = lane & 15;
#pragma unroll
    for (int m = 0; m < 4; ++m) {
#pragma unroll
        for (int n = 0; n < 4; ++n) {
            float s[4];
#pragma unroll
            for (int j = 0; j < 4; ++j)
                s[j] = 1.0f / (1.0f + __expf(-acc[m][n][j]));
            const int gr0 = bi * 128 + wr * 64 + m * 16 + rj;
            const int gc  = bj * 128 + wc * 64 + n * 16 + cc;
#pragma unroll
            for (int j = 0; j < 4; ++j)
                __builtin_nontemporal_store(s[j], out + (size_t)(gr0 + j) * NNODE + gc);
            if (bi != bj) {
                const int mr = bj * 128 + wc * 64 + n * 16 + cc;
                const int mc = bi * 128 + wr * 64 + m * 16 + rj;
                f32x4 v = {s[0], s[1], s[2], s[3]};
                __builtin_nontemporal_store(v, (f32x4*)(out + (size_t)mr * NNODE + mc));
            }
        }
    }
}

// ---------------- launch ----------------
extern "C" void kernel_launch(void* const* d_in, const int* in_sizes, int n_in,
                              void* d_out, int out_size, void* d_ws, size_t ws_size,
                              hipStream_t stream) {
    const float* x_self     = (const float*)d_in[0];
    const float* x_neighbor = (const float*)d_in[1];
    const int*   ei         = (const int*)d_in[2];
    const float* w_in_self  = (const float*)d_in[3];
    const float* b_in_self  = (const float*)d_in[4];
    const float* w_out_self = (const float*)d_in[5];
    const float* b_out_self = (const float*)d_in[6];
    const float* gw1        = (const float*)d_in[7];
    const float* gb1        = (const float*)d_in[8];
    const float* gw2        = (const float*)d_in[9];
    const float* gb2        = (const float*)d_in[10];
    const float* w_out      = (const float*)d_in[11];
    const float* b_out      = (const float*)d_in[12];
    float* out = (float*)d_out;

    char* ws = (char*)d_ws;
    const size_t MB = 1024 * 1024;
    const size_t KB = 1024;
    int*   cnt       = (int*)(ws + 0);
    int*   row_start = (int*)(ws + 32 * KB);
    int*   cursor    = (int*)(ws + 96 * KB);
    float* dinv      = (float*)(ws + 128 * KB);
    float* bc        = (float*)(ws + 192 * KB);
    int*   slist     = (int*)(ws + 2 * MB);
    float* wlist     = (float*)(ws + 3 * MB);
    unsigned short* xsh = (unsigned short*)(ws + 4 * MB);
    unsigned short* xsl = (unsigned short*)(ws + 12 * MB);
    unsigned short* xnh = (unsigned short*)(ws + 20 * MB);
    unsigned short* xnl = (unsigned short*)(ws + 28 * MB);
    unsigned short* l1h = (unsigned short*)(ws + 36 * MB);
    unsigned short* l1l = (unsigned short*)(ws + 44 * MB);
    unsigned short* hcb = (unsigned short*)(ws + 52 * MB);  // 4 MB bf16 [8192,256]
    unsigned short* t1b = (unsigned short*)(ws + 60 * MB);  // 4 MB bf16
    unsigned short* g2h = (unsigned short*)(ws + 68 * MB);
    unsigned short* g2l = (unsigned short*)(ws + 72 * MB);
    unsigned short* zhi = (unsigned short*)(ws + 76 * MB);
    unsigned short* zlo = (unsigned short*)(ws + 84 * MB);
    unsigned short* wAt_h = (unsigned short*)(ws + 92 * MB);   // [768,512]
    unsigned short* wAt_l = (unsigned short*)(ws + 93 * MB);
    unsigned short* wost_h = (unsigned short*)(ws + 94 * MB);  // [256,1024]
    unsigned short* wost_l = (unsigned short*)(ws + 95 * MB);
    unsigned short* wot_h  = (unsigned short*)(ws + 96 * MB);  // [256,768]
    unsigned short* wot_l  = (unsigned short*)(ws + 97 * MB);

    const int* srcA = ei;          // edge_index[0]
    const int* dstA = ei + NEDGE;  // edge_index[1]

    // prep (splits + weight transforms + cnt zero), independent of CSR
    k_prep<<<9057, 256, 0, stream>>>(x_self, x_neighbor, w_in_self, w_out_self, w_out,
                                     gw1, gw2, gb1, xsh, xsl, xnh, xnl,
                                     wAt_h, wAt_l, wost_h, wost_l, wot_h, wot_l, bc, cnt);

    // CSR build
    k_count<<<NEDGE / 256, 256, 0, stream>>>(dstA, cnt, NEDGE);
    k_scan<<<1, 256, 0, stream>>>(cnt, row_start, cursor, dinv);
    k_fill_csr2<<<NEDGE / 256, 256, 0, stream>>>(srcA, dstA, cursor, dinv, slist, wlist, NEDGE);

    // fused GEMM: xs @ [Win | Wc] -> l1 (relu, split) + hc (bf16)
    k_gemm128_A<<<768, 256, 0, stream>>>(
        xsh, xsl, wAt_h, wAt_l, b_in_self, l1h, l1l, hcb);

    // double aggregation (wave-per-node, bf16 tables): t1 = S hc ; g2 = S t1 + svec*bc + gb2
    k_agg4<0><<<NNODE / 4, 256, 0, stream>>>(row_start, slist, wlist, dinv, hcb,
                                             nullptr, nullptr, t1b, nullptr, nullptr);
    k_agg4<1><<<NNODE / 4, 256, 0, stream>>>(row_start, slist, wlist, dinv, t1b,
                                             bc, gb2, nullptr, g2h, g2l);

    // z = [ [xs|l1]@wost + b_os , [xn|g2]@wot + b_o ]  (split into zhi/zlo)
    k_gemm128_Z<<<512, 256, 0, stream>>>(
        xsh, xsl, l1h, l1l, xnh, xnl, g2h, g2l,
        wost_h, wost_l, wot_h, wot_l, b_out_self, b_out, zhi, zlo);

    // out = sigmoid(z z^T), 128^2 counted-vmcnt pipeline
    k_zzt_mfma<<<2080, 256, 0, stream>>>(zhi, zlo, out);
}

// Round 13
// 321.348 us; speedup vs baseline: 1.2786x; 1.1023x over previous
//
#include <hip/hip_runtime.h>
#include <cstdint>
#include <cstddef>

#define NNODE 8192
#define NEDGE 262144

typedef __attribute__((ext_vector_type(8))) short bf16x8;
typedef __attribute__((ext_vector_type(4))) float f32x4;
typedef __attribute__((ext_vector_type(4))) int i32x4;

// ---------------- bf16 split helpers ----------------
__device__ __forceinline__ unsigned short f2bf_rn(float x) {
    unsigned u = __float_as_uint(x);
    u = (u + 0x7FFFu + ((u >> 16) & 1u)) >> 16;
    return (unsigned short)u;
}
__device__ __forceinline__ float bf2f(unsigned short h) {
    return __uint_as_float(((unsigned)h) << 16);
}

__device__ __forceinline__ void gload16(const char* gp, char* lp) {
    __builtin_amdgcn_global_load_lds((const __attribute__((address_space(1))) void*)gp,
                                     (__attribute__((address_space(3))) void*)lp, 16, 0, 0);
}

// ---------------- CSR kernels ----------------

__global__ void k_count(const int* __restrict__ dst, int* __restrict__ cnt, int n) {
    int i = blockIdx.x * blockDim.x + threadIdx.x;
    if (i < n) atomicAdd(&cnt[dst[i]], 1);
}

__global__ __launch_bounds__(256) void k_scan(const int* __restrict__ cnt,
                                              int* __restrict__ row_start,
                                              int* __restrict__ cursor,
                                              float* __restrict__ dinv) {
    __shared__ int part[256];
    const int tid = threadIdx.x;
    const int PER = NNODE / 256;  // 32
    const int base = tid * PER;
    int loc[PER];
    int sum = 0;
#pragma unroll
    for (int i = 0; i < PER; ++i) { loc[i] = cnt[base + i]; sum += loc[i]; }
    part[tid] = sum;
    __syncthreads();
    if (tid == 0) {
        int r = 0;
        for (int i = 0; i < 256; ++i) { int t = part[i]; part[i] = r; r += t; }
    }
    __syncthreads();
    int run = part[tid];
#pragma unroll
    for (int i = 0; i < PER; ++i) {
        row_start[base + i] = run;
        cursor[base + i] = run;
        dinv[base + i] = rsqrtf((float)loc[i] + 1.0f);  // deg = in-degree + self loop
        run += loc[i];
    }
    if (tid == 255) row_start[NNODE] = run;
}

__global__ void k_fill_csr2(const int* __restrict__ src, const int* __restrict__ dst,
                            int* __restrict__ cursor, const float* __restrict__ dinv,
                            int* __restrict__ slist, float* __restrict__ wlist, int n) {
    int e = blockIdx.x * blockDim.x + threadIdx.x;
    if (e < n) {
        int d = dst[e];
        int s = src[e];
        int pos = atomicAdd(&cursor[d], 1);
        slist[pos] = s;
        wlist[pos] = dinv[s] * dinv[d];
    }
}

// ---------------- mega prep kernel (also zeroes cnt) ----------------
__device__ __forceinline__ void split_wt_tile(const float* __restrict__ W, int K, int N,
                                              int k0, int n0,
                                              unsigned short* __restrict__ Oh,
                                              unsigned short* __restrict__ Ol,
                                              float (*t)[33]) {
    const int c = threadIdx.x & 31, r8 = threadIdx.x >> 5;
#pragma unroll
    for (int i = 0; i < 4; ++i) {
        int r = r8 + i * 8;
        t[r][c] = W[(size_t)(k0 + r) * N + n0 + c];
    }
    __syncthreads();
#pragma unroll
    for (int i = 0; i < 4; ++i) {
        int r = r8 + i * 8;
        float x = t[c][r];
        unsigned short h = f2bf_rn(x);
        Oh[(size_t)(n0 + r) * K + k0 + c] = h;
        Ol[(size_t)(n0 + r) * K + k0 + c] = f2bf_rn(x - bf2f(h));
    }
}

__global__ __launch_bounds__(256) void k_prep(
    const float* __restrict__ x_self, const float* __restrict__ x_neighbor,
    const float* __restrict__ w_in_self, const float* __restrict__ w_out_self,
    const float* __restrict__ w_out, const float* __restrict__ gw1,
    const float* __restrict__ gw2, const float* __restrict__ gb1,
    unsigned short* __restrict__ xsh, unsigned short* __restrict__ xsl,
    unsigned short* __restrict__ xnh, unsigned short* __restrict__ xnl,
    unsigned short* __restrict__ wAt_h, unsigned short* __restrict__ wAt_l,
    unsigned short* __restrict__ wost_h, unsigned short* __restrict__ wost_l,
    unsigned short* __restrict__ wot_h, unsigned short* __restrict__ wot_l,
    float* __restrict__ bc, int* __restrict__ cnt) {
    __shared__ float t[32][33];
    const int b = blockIdx.x;
    const int tid = threadIdx.x;
    if (b < 8192) {  // splits
        const float* src = (b < 4096) ? x_self : x_neighbor;
        unsigned short* oh = (b < 4096) ? xsh : xnh;
        unsigned short* ol = (b < 4096) ? xsl : xnl;
        const int i = (b & 4095) * 256 + tid;
        float4 v = ((const float4*)src)[i];
        float x[4] = {v.x, v.y, v.z, v.w};
        unsigned short h[4], l[4];
#pragma unroll
        for (int j = 0; j < 4; ++j) {
            h[j] = f2bf_rn(x[j]);
            l[j] = f2bf_rn(x[j] - bf2f(h[j]));
        }
        ((ushort4*)oh)[i] = make_ushort4(h[0], h[1], h[2], h[3]);
        ((ushort4*)ol)[i] = make_ushort4(l[0], l[1], l[2], l[3]);
    } else if (b < 8448) {
        const int b2 = b - 8192;
        split_wt_tile(w_in_self, 512, 512, (b2 & 15) * 32, (b2 >> 4) * 32, wAt_h, wAt_l, t);
    } else if (b < 8576) {  // Wc = gw1 @ gw2 on the fly
        const int b3 = b - 8448;
        const int k0 = (b3 & 15) * 32, n0 = (b3 >> 4) * 32;
        const int nloc = tid & 31, kg = tid >> 5;
        float a[4] = {0.f, 0.f, 0.f, 0.f};
        for (int c = 0; c < 512; ++c) {
            float g2v = gw2[(size_t)c * 256 + n0 + nloc];
#pragma unroll
            for (int i = 0; i < 4; ++i)
                a[i] += gw1[(size_t)(k0 + kg * 4 + i) * 512 + c] * g2v;
        }
#pragma unroll
        for (int i = 0; i < 4; ++i) {
            unsigned short hh = f2bf_rn(a[i]);
            wAt_h[(size_t)(512 + n0 + nloc) * 512 + k0 + kg * 4 + i] = hh;
            wAt_l[(size_t)(512 + n0 + nloc) * 512 + k0 + kg * 4 + i] = f2bf_rn(a[i] - bf2f(hh));
        }
    } else if (b < 8832) {
        const int b4 = b - 8576;
        split_wt_tile(w_out_self, 1024, 256, (b4 & 31) * 32, (b4 >> 5) * 32, wost_h, wost_l, t);
    } else if (b < 9024) {
        const int b5 = b - 8832;
        split_wt_tile(w_out, 768, 256, (b5 % 24) * 32, (b5 / 24) * 32, wot_h, wot_l, t);
    } else if (b == 9024) {
        float a = 0.0f;
        for (int c = 0; c < 512; ++c) a += gb1[c] * gw2[(size_t)c * 256 + tid];
        bc[tid] = a;
    } else {  // zero cnt: blocks 9025..9056
        cnt[(b - 9025) * 256 + tid] = 0;
    }
}

// ---------------- shared GEMM pieces (128x64 tile, 4 waves, BK=32) ----------------
__device__ __forceinline__ void stage_g(char* buf,
                                        const char* aH, const char* aL, size_t strA,
                                        const char* bH, const char* bL, size_t strB,
                                        int rloc, int w) {
#pragma unroll
    for (int i = 0; i < 2; ++i) {
        const size_t r = (size_t)(rloc + i * 64);
        char* lp = buf + i * 4096 + w * 1024;
        gload16(aH + r * strA, lp);
        gload16(aL + r * strA, lp + 8192);
    }
    gload16(bH + (size_t)rloc * strB, buf + 16384 + w * 1024);
    gload16(bL + (size_t)rloc * strB, buf + 20480 + w * 1024);
}

__device__ __forceinline__ void core_2x4(const char* cur, int w, int sread, int lane,
                                         f32x4 acc[2][4]) {
    bf16x8 ah[2], al[2], bh[4], bl[4];
#pragma unroll
    for (int m = 0; m < 2; ++m) {
        const int row = w * 32 + m * 16 + (lane & 15);
        ah[m] = *(const bf16x8*)(cur + row * 64 + sread);
        al[m] = *(const bf16x8*)(cur + 8192 + row * 64 + sread);
    }
#pragma unroll
    for (int n = 0; n < 4; ++n) {
        const int row = n * 16 + (lane & 15);
        bh[n] = *(const bf16x8*)(cur + 16384 + row * 64 + sread);
        bl[n] = *(const bf16x8*)(cur + 20480 + row * 64 + sread);
    }
#pragma unroll
    for (int m = 0; m < 2; ++m)
#pragma unroll
        for (int n = 0; n < 4; ++n) {
            acc[m][n] = __builtin_amdgcn_mfma_f32_16x16x32_bf16(ah[m], bh[n], acc[m][n], 0, 0, 0);
            acc[m][n] = __builtin_amdgcn_mfma_f32_16x16x32_bf16(ah[m], bl[n], acc[m][n], 0, 0, 0);
            acc[m][n] = __builtin_amdgcn_mfma_f32_16x16x32_bf16(al[m], bh[n], acc[m][n], 0, 0, 0);
        }
}

// ---------------- GEMM-A: xs @ [Win | Wc] -> l1 (relu,split) + hc (bf16) ----------------
__global__ __launch_bounds__(256) void k_gemm128_A(
    const unsigned short* __restrict__ xsh, const unsigned short* __restrict__ xsl,
    const unsigned short* __restrict__ wAt_h, const unsigned short* __restrict__ wAt_l,
    const float* __restrict__ bias,
    unsigned short* __restrict__ l1h, unsigned short* __restrict__ l1l,
    unsigned short* __restrict__ hcb) {
    __shared__ __align__(16) char smem[49152];
    const int tid = threadIdx.x, lane = tid & 63, w = tid >> 6;
    const int t0 = blockIdx.x;
    const int s = (t0 & 7) * 96 + (t0 >> 3);
    const int bm = (s / 12) * 128, bn = (s % 12) * 64;
    const int rloc = w * 16 + (lane >> 2);
    const int swz_src = ((lane & 3) ^ ((lane >> 3) & 3)) * 16;
    const int sread = ((lane >> 4) ^ ((lane >> 1) & 3)) * 16;
    const char* Ah = (const char*)xsh + (size_t)bm * 1024 + swz_src;
    const char* Al = (const char*)xsl + (size_t)bm * 1024 + swz_src;
    const char* Bh = (const char*)wAt_h + (size_t)bn * 1024 + swz_src;
    const char* Bl = (const char*)wAt_l + (size_t)bn * 1024 + swz_src;

    f32x4 acc[2][4] = {};
    stage_g(smem,         Ah,      Al,      1024, Bh,      Bl,      1024, rloc, w);
    stage_g(smem + 24576, Ah + 64, Al + 64, 1024, Bh + 64, Bl + 64, 1024, rloc, w);
    for (int ks = 0; ks < 16; ++ks) {
        if (ks < 15) asm volatile("s_waitcnt vmcnt(6)" ::: "memory");
        else         asm volatile("s_waitcnt vmcnt(0)" ::: "memory");
        __builtin_amdgcn_s_barrier();
        __builtin_amdgcn_sched_barrier(0);
        core_2x4(smem + (ks & 1) * 24576, w, sread, lane, acc);
        __builtin_amdgcn_sched_barrier(0);
        __builtin_amdgcn_s_barrier();
        if (ks < 14) {
            const int kb = (ks + 2) * 64;
            stage_g(smem + (ks & 1) * 24576, Ah + kb, Al + kb, 1024,
                    Bh + kb, Bl + kb, 1024, rloc, w);
        }
    }

    const int rj = (lane >> 4) * 4, cc = lane & 15;
#pragma unroll
    for (int m = 0; m < 2; ++m) {
#pragma unroll
        for (int n = 0; n < 4; ++n) {
            const int col = bn + n * 16 + cc;
#pragma unroll
            for (int j = 0; j < 4; ++j) {
                const int row = bm + w * 32 + m * 16 + rj + j;
                float x = acc[m][n][j];
                if (col < 512) {
                    x += bias[col];
                    x = fmaxf(x, 0.0f);
                    unsigned short h = f2bf_rn(x);
                    l1h[(size_t)row * 512 + col] = h;
                    l1l[(size_t)row * 512 + col] = f2bf_rn(x - bf2f(h));
                } else {
                    hcb[(size_t)row * 256 + (col - 512)] = f2bf_rn(x);
                }
            }
        }
    }
}

// ---------------- GEMM-Z: z halves, concat-K -> fp32 z. grid 512 = 8 x 64 ----------------
__global__ __launch_bounds__(256) void k_gemm128_Z(
    const unsigned short* __restrict__ xsh, const unsigned short* __restrict__ xsl,
    const unsigned short* __restrict__ l1h, const unsigned short* __restrict__ l1l,
    const unsigned short* __restrict__ xnh, const unsigned short* __restrict__ xnl,
    const unsigned short* __restrict__ g2h, const unsigned short* __restrict__ g2l,
    const unsigned short* __restrict__ wost_h, const unsigned short* __restrict__ wost_l,
    const unsigned short* __restrict__ wot_h, const unsigned short* __restrict__ wot_l,
    const float* __restrict__ b_out_self, const float* __restrict__ b_out,
    float* __restrict__ zf) {
    __shared__ __align__(16) char smem[49152];
    const int t0 = blockIdx.x;
    const int s = (t0 & 7) * 64 + (t0 >> 3);
    const int half = s & 1;
    const int rem = s >> 1;
    const int bn = (rem & 3) * 64;
    const int bm = (rem >> 2) * 128;
    const int tid = threadIdx.x, lane = tid & 63, w = tid >> 6;
    const int rloc = w * 16 + (lane >> 2);
    const int swz_src = ((lane & 3) ^ ((lane >> 3) & 3)) * 16;
    const int sread = ((lane >> 4) ^ ((lane >> 1) & 3)) * 16;

    const unsigned short *A1h, *A1l, *A2h, *A2l, *Wh, *Wl;
    const float* bias;
    int Ktot;
    size_t strA2, strB;
    if (half == 0) {
        A1h = xsh; A1l = xsl; A2h = l1h; A2l = l1l; strA2 = 1024;
        Wh = wost_h; Wl = wost_l; strB = 2048; Ktot = 1024; bias = b_out_self;
    } else {
        A1h = xnh; A1l = xnl; A2h = g2h; A2l = g2l; strA2 = 512;
        Wh = wot_h; Wl = wot_l; strB = 1536; Ktot = 768; bias = b_out;
    }
    const int nsteps = Ktot / 32;
    const char* Bh = (const char*)Wh + (size_t)bn * strB + swz_src;
    const char* Bl = (const char*)Wl + (size_t)bn * strB + swz_src;

    auto asrc = [&](int k0, const char*& sh, const char*& sl, size_t& st) {
        if (k0 < 512) {
            sh = (const char*)A1h + (size_t)bm * 1024 + (size_t)k0 * 2 + swz_src;
            sl = (const char*)A1l + (size_t)bm * 1024 + (size_t)k0 * 2 + swz_src;
            st = 1024;
        } else {
            sh = (const char*)A2h + (size_t)bm * strA2 + (size_t)(k0 - 512) * 2 + swz_src;
            sl = (const char*)A2l + (size_t)bm * strA2 + (size_t)(k0 - 512) * 2 + swz_src;
            st = strA2;
        }
    };

    f32x4 acc[2][4] = {};
    {
        const char *sh, *sl; size_t st;
        asrc(0, sh, sl, st);
        stage_g(smem, sh, sl, st, Bh, Bl, strB, rloc, w);
        asrc(32, sh, sl, st);
        stage_g(smem + 24576, sh, sl, st, Bh + 64, Bl + 64, strB, rloc, w);
    }
    for (int ks = 0; ks < nsteps; ++ks) {
        if (ks < nsteps - 1) asm volatile("s_waitcnt vmcnt(6)" ::: "memory");
        else                 asm volatile("s_waitcnt vmcnt(0)" ::: "memory");
        __builtin_amdgcn_s_barrier();
        __builtin_amdgcn_sched_barrier(0);
        core_2x4(smem + (ks & 1) * 24576, w, sread, lane, acc);
        __builtin_amdgcn_sched_barrier(0);
        __builtin_amdgcn_s_barrier();
        if (ks + 2 < nsteps) {
            const char *sh, *sl; size_t st;
            asrc((ks + 2) * 32, sh, sl, st);
            stage_g(smem + (ks & 1) * 24576, sh, sl, st,
                    Bh + (size_t)(ks + 2) * 64, Bl + (size_t)(ks + 2) * 64, strB, rloc, w);
        }
    }

    const int rj = (lane >> 4) * 4, cc = lane & 15;
    const int zoff = half * 256;
#pragma unroll
    for (int m = 0; m < 2; ++m) {
#pragma unroll
        for (int n = 0; n < 4; ++n) {
            const int col = bn + n * 16 + cc;  // 0..255 within half
            const float bv = bias[col];
#pragma unroll
            for (int j = 0; j < 4; ++j) {
                const int row = bm + w * 32 + m * 16 + rj + j;
                zf[(size_t)row * 512 + zoff + col] = acc[m][n][j] + bv;
            }
        }
    }
}

// ---------------- GCN aggregation, wave-per-node, bf16 table, ushort4 gathers ----------------
template <int MODE>
__global__ __launch_bounds__(256) void k_agg4(
    const int* __restrict__ row_start, const int* __restrict__ slist,
    const float* __restrict__ wlist, const float* __restrict__ dinv,
    const unsigned short* __restrict__ h,
    const float* __restrict__ bc, const float* __restrict__ b2,
    unsigned short* __restrict__ t1,
    unsigned short* __restrict__ oh, unsigned short* __restrict__ ol) {
    const int n = blockIdx.x * 4 + (threadIdx.x >> 6);
    const int lane = threadIdx.x & 63;
    const int c0 = lane * 4;
    const float di = dinv[n];

    ushort4 selfv = ((const ushort4*)(h + (size_t)n * 256))[lane];
    float acc[4];
    acc[0] = di * di * bf2f(selfv.x);
    acc[1] = di * di * bf2f(selfv.y);
    acc[2] = di * di * bf2f(selfv.z);
    acc[3] = di * di * bf2f(selfv.w);
    float sv = di * di;

    const int e0 = row_start[n], e1 = row_start[n + 1];
    int j = e0;
    for (; j + 4 <= e1; j += 4) {
        int ss[4];
        float ww[4];
        ushort4 rv[4];
#pragma unroll
        for (int u = 0; u < 4; ++u) { ss[u] = slist[j + u]; ww[u] = wlist[j + u]; }
#pragma unroll
        for (int u = 0; u < 4; ++u)
            rv[u] = ((const ushort4*)(h + (size_t)ss[u] * 256))[lane];
#pragma unroll
        for (int u = 0; u < 4; ++u) {
            acc[0] += ww[u] * bf2f(rv[u].x);
            acc[1] += ww[u] * bf2f(rv[u].y);
            acc[2] += ww[u] * bf2f(rv[u].z);
            acc[3] += ww[u] * bf2f(rv[u].w);
            if (MODE) sv += ww[u];
        }
    }
    for (; j < e1; ++j) {
        const float wv = wlist[j];
        ushort4 rv = ((const ushort4*)(h + (size_t)slist[j] * 256))[lane];
        acc[0] += wv * bf2f(rv.x);
        acc[1] += wv * bf2f(rv.y);
        acc[2] += wv * bf2f(rv.z);
        acc[3] += wv * bf2f(rv.w);
        if (MODE) sv += wv;
    }

    if (MODE == 0) {
        ushort4 o;
        o.x = f2bf_rn(acc[0]); o.y = f2bf_rn(acc[1]);
        o.z = f2bf_rn(acc[2]); o.w = f2bf_rn(acc[3]);
        ((ushort4*)(t1 + (size_t)n * 256))[lane] = o;
    } else {
        ushort4 vh, vl;
        float x0 = acc[0] + sv * bc[c0 + 0] + b2[c0 + 0];
        float x1 = acc[1] + sv * bc[c0 + 1] + b2[c0 + 1];
        float x2 = acc[2] + sv * bc[c0 + 2] + b2[c0 + 2];
        float x3 = acc[3] + sv * bc[c0 + 3] + b2[c0 + 3];
        vh.x = f2bf_rn(x0); vl.x = f2bf_rn(x0 - bf2f(vh.x));
        vh.y = f2bf_rn(x1); vl.y = f2bf_rn(x1 - bf2f(vh.y));
        vh.z = f2bf_rn(x2); vl.z = f2bf_rn(x2 - bf2f(vh.z));
        vh.w = f2bf_rn(x3); vl.w = f2bf_rn(x3 - bf2f(vh.w));
        ((ushort4*)(oh + (size_t)n * 256))[lane] = vh;
        ((ushort4*)(ol + (size_t)n * 256))[lane] = vl;
    }
}

// ---------------- quantize z (fp32) -> qa + qb (i8) with per-row scale ----------------
// wave per row; lane handles 8 cols. z ~ s*(a + b/256), s = amax/127.
__global__ __launch_bounds__(256) void k_quant(const float* __restrict__ z,
                                               signed char* __restrict__ qa,
                                               signed char* __restrict__ qb,
                                               float* __restrict__ scl) {
    const int n = blockIdx.x * 4 + (threadIdx.x >> 6);
    const int lane = threadIdx.x & 63;
    const float* zr = z + (size_t)n * 512;
    float4 v0 = ((const float4*)zr)[lane * 2];
    float4 v1 = ((const float4*)zr)[lane * 2 + 1];
    float xs[8] = {v0.x, v0.y, v0.z, v0.w, v1.x, v1.y, v1.z, v1.w};
    float m = 0.0f;
#pragma unroll
    for (int j = 0; j < 8; ++j) m = fmaxf(m, fabsf(xs[j]));
#pragma unroll
    for (int off = 32; off; off >>= 1) m = fmaxf(m, __shfl_xor(m, off));
    m = fmaxf(m, 1e-20f);
    const float s = m * (1.0f / 127.0f);
    const float inv = 127.0f / m;
    if (lane == 0) scl[n] = s;
    unsigned long long pa = 0, pb = 0;
#pragma unroll
    for (int j = 0; j < 8; ++j) {
        float af = rintf(xs[j] * inv);
        af = fminf(fmaxf(af, -127.0f), 127.0f);
        int ia = (int)af;
        float r = xs[j] - af * s;
        int ib = (int)rintf(r * inv * 256.0f);
        ib = ib > 127 ? 127 : (ib < -128 ? -128 : ib);
        pa |= ((unsigned long long)(unsigned char)(ia & 0xff)) << (8 * j);
        pb |= ((unsigned long long)(unsigned char)(ib & 0xff)) << (8 * j);
    }
    *(unsigned long long*)(qa + (size_t)n * 512 + lane * 8) = pa;
    *(unsigned long long*)(qb + (size_t)n * 512 + lane * 8) = pb;
}

// ---------------- out = sigmoid(Z Z^T) via split-i8 MFMA, 128^2, counted-vmcnt ----------------
// score = s_i*s_j*(a.a^T + (a.b^T + b.a^T)/256)  [b.b^T dropped, ~0.005 post-sigmoid max]
// Structure identical to the proven r9 kernel; row stride 512B, 8 K-steps of K=64.
__device__ __forceinline__ void q8_stage(char* buf, const char* s0, const char* s1,
                                         const char* s2, const char* s3,
                                         int rloc, int swz_src, int w, int kbyte) {
    const char* srcs[4] = {s0, s1, s2, s3};
#pragma unroll
    for (int tile = 0; tile < 4; ++tile) {
#pragma unroll
        for (int i = 0; i < 2; ++i) {
            const char* gp = srcs[tile] + (size_t)(rloc + i * 64) * 512 + kbyte + swz_src;
            char* lp = buf + tile * 8192 + i * 4096 + w * 1024;
            gload16(gp, lp);
        }
    }
}

__global__ __launch_bounds__(256) void k_zzt_q8(const signed char* __restrict__ qa,
                                                const signed char* __restrict__ qb,
                                                const float* __restrict__ scl,
                                                float* __restrict__ out) {
    __shared__ __align__(16) char smem[65536];  // 2 x 32KB
    const int tid = threadIdx.x;
    const int lane = tid & 63;
    const int w = tid >> 6;
    const int wr = w >> 1, wc = w & 1;

    // XCD swizzle (2080 = 8 x 260, bijective), then lower-triangular decode (bi >= bj)
    const int t0 = blockIdx.x;
    const int t = (t0 & 7) * 260 + (t0 >> 3);
    int bi = (int)((sqrtf(8.0f * (float)t + 1.0f) - 1.0f) * 0.5f);
    while ((bi + 1) * (bi + 2) / 2 <= t) ++bi;
    while (bi * (bi + 1) / 2 > t) --bi;
    const int bj = t - bi * (bi + 1) / 2;

    const char* s0 = (const char*)qa + (size_t)(bi * 128) * 512;
    const char* s1 = (const char*)qb + (size_t)(bi * 128) * 512;
    const char* s2 = (const char*)qa + (size_t)(bj * 128) * 512;
    const char* s3 = (const char*)qb + (size_t)(bj * 128) * 512;

    const int rloc = w * 16 + (lane >> 2);
    const int swz_src = ((lane & 3) ^ ((lane >> 3) & 3)) * 16;
    const int sread = ((lane >> 4) ^ ((lane >> 1) & 3)) * 16;

    i32x4 acc0[4][4] = {};
    i32x4 acc1[4][4] = {};

    q8_stage(smem,         s0, s1, s2, s3, rloc, swz_src, w, 0);
    q8_stage(smem + 32768, s0, s1, s2, s3, rloc, swz_src, w, 64);

    for (int ks = 0; ks < 8; ++ks) {
        if (ks < 7) asm volatile("s_waitcnt vmcnt(8)" ::: "memory");
        else        asm volatile("s_waitcnt vmcnt(0)" ::: "memory");
        __builtin_amdgcn_s_barrier();
        __builtin_amdgcn_sched_barrier(0);
        const char* cur = smem + (ks & 1) * 32768;

        i32x4 ai[4], av[4], aj[4], bv[4];
        const char* pa = cur + (wr * 64 + (lane & 15)) * 64 + sread;
        const char* pb = cur + 16384 + (wc * 64 + (lane & 15)) * 64 + sread;
#pragma unroll
        for (int m = 0; m < 4; ++m) {
            ai[m] = *(const i32x4*)(pa + m * 1024);
            av[m] = *(const i32x4*)(pa + 8192 + m * 1024);
        }
#pragma unroll
        for (int n = 0; n < 4; ++n) {
            aj[n] = *(const i32x4*)(pb + n * 1024);
            bv[n] = *(const i32x4*)(pb + 8192 + n * 1024);
        }
        __builtin_amdgcn_s_setprio(1);
#pragma unroll
        for (int m = 0; m < 4; ++m)
#pragma unroll
            for (int n = 0; n < 4; ++n) {
                acc0[m][n] = __builtin_amdgcn_mfma_i32_16x16x64_i8(ai[m], aj[n], acc0[m][n], 0, 0, 0);
                acc1[m][n] = __builtin_amdgcn_mfma_i32_16x16x64_i8(ai[m], bv[n], acc1[m][n], 0, 0, 0);
                acc1[m][n] = __builtin_amdgcn_mfma_i32_16x16x64_i8(av[m], aj[n], acc1[m][n], 0, 0, 0);
            }
        __builtin_amdgcn_s_setprio(0);
        __builtin_amdgcn_sched_barrier(0);
        __builtin_amdgcn_s_barrier();
        if (ks < 6)
            q8_stage(smem + (ks & 1) * 32768, s0, s1, s2, s3, rloc, swz_src, w,
                     (ks + 2) * 64);
    }

    // epilogue: scale, sigmoid, NT stores; direct tile + mirror
    const int rj = (lane >> 4) * 4;
    const int cc = lane & 15;
    float sJ[4];
#pragma unroll
    for (int n = 0; n < 4; ++n) sJ[n] = scl[bj * 128 + wc * 64 + n * 16 + cc];
#pragma unroll
    for (int m = 0; m < 4; ++m) {
#pragma unroll
        for (int n = 0; n < 4; ++n) {
            float s[4];
#pragma unroll
            for (int j = 0; j < 4; ++j) {
                const float sI = scl[bi * 128 + wr * 64 + m * 16 + rj + j];
                const float sc = sI * sJ[n] *
                    ((float)acc0[m][n][j] + (float)acc1[m][n][j] * 0.00390625f);
                s[j] = 1.0f / (1.0f + __expf(-sc));
            }
            const int gr0 = bi * 128 + wr * 64 + m * 16 + rj;
            const int gc  = bj * 128 + wc * 64 + n * 16 + cc;
#pragma unroll
            for (int j = 0; j < 4; ++j)
                __builtin_nontemporal_store(s[j], out + (size_t)(gr0 + j) * NNODE + gc);
            if (bi != bj) {
                const int mr = bj * 128 + wc * 64 + n * 16 + cc;
                const int mc = bi * 128 + wr * 64 + m * 16 + rj;
                f32x4 v = {s[0], s[1], s[2], s[3]};
                __builtin_nontemporal_store(v, (f32x4*)(out + (size_t)mr * NNODE + mc));
            }
        }
    }
}

// ---------------- launch ----------------
extern "C" void kernel_launch(void* const* d_in, const int* in_sizes, int n_in,
                              void* d_out, int out_size, void* d_ws, size_t ws_size,
                              hipStream_t stream) {
    const float* x_self     = (const float*)d_in[0];
    const float* x_neighbor = (const float*)d_in[1];
    const int*   ei         = (const int*)d_in[2];
    const float* w_in_self  = (const float*)d_in[3];
    const float* b_in_self  = (const float*)d_in[4];
    const float* w_out_self = (const float*)d_in[5];
    const float* b_out_self = (const float*)d_in[6];
    const float* gw1        = (const float*)d_in[7];
    const float* gb1        = (const float*)d_in[8];
    const float* gw2        = (const float*)d_in[9];
    const float* gb2        = (const float*)d_in[10];
    const float* w_out      = (const float*)d_in[11];
    const float* b_out      = (const float*)d_in[12];
    float* out = (float*)d_out;

    char* ws = (char*)d_ws;
    const size_t MB = 1024 * 1024;
    const size_t KB = 1024;
    int*   cnt       = (int*)(ws + 0);
    int*   row_start = (int*)(ws + 32 * KB);
    int*   cursor    = (int*)(ws + 96 * KB);
    float* dinv      = (float*)(ws + 128 * KB);
    float* bc        = (float*)(ws + 192 * KB);
    int*   slist     = (int*)(ws + 2 * MB);
    float* wlist     = (float*)(ws + 3 * MB);
    unsigned short* xsh = (unsigned short*)(ws + 4 * MB);
    unsigned short* xsl = (unsigned short*)(ws + 12 * MB);
    unsigned short* xnh = (unsigned short*)(ws + 20 * MB);
    unsigned short* xnl = (unsigned short*)(ws + 28 * MB);
    unsigned short* l1h = (unsigned short*)(ws + 36 * MB);
    unsigned short* l1l = (unsigned short*)(ws + 44 * MB);
    unsigned short* hcb = (unsigned short*)(ws + 52 * MB);  // 4 MB bf16 [8192,256]
    unsigned short* t1b = (unsigned short*)(ws + 60 * MB);  // 4 MB bf16
    unsigned short* g2h = (unsigned short*)(ws + 68 * MB);
    unsigned short* g2l = (unsigned short*)(ws + 72 * MB);
    float*          zf  = (float*)(ws + 76 * MB);           // 16 MB fp32 [8192,512]
    unsigned short* wAt_h = (unsigned short*)(ws + 92 * MB);   // [768,512]
    unsigned short* wAt_l = (unsigned short*)(ws + 93 * MB);
    unsigned short* wost_h = (unsigned short*)(ws + 94 * MB);  // [256,1024]
    unsigned short* wost_l = (unsigned short*)(ws + 95 * MB);
    unsigned short* wot_h  = (unsigned short*)(ws + 96 * MB);  // [256,768]
    unsigned short* wot_l  = (unsigned short*)(ws + 97 * MB);
    signed char* qa  = (signed char*)(ws + 100 * MB);          // 4 MB i8 [8192,512]
    signed char* qb  = (signed char*)(ws + 104 * MB);          // 4 MB
    float*       scl = (float*)(ws + 108 * MB);                // 32 KB

    const int* srcA = ei;          // edge_index[0]
    const int* dstA = ei + NEDGE;  // edge_index[1]

    // prep (splits + weight transforms + cnt zero), independent of CSR
    k_prep<<<9057, 256, 0, stream>>>(x_self, x_neighbor, w_in_self, w_out_self, w_out,
                                     gw1, gw2, gb1, xsh, xsl, xnh, xnl,
                                     wAt_h, wAt_l, wost_h, wost_l, wot_h, wot_l, bc, cnt);

    // CSR build
    k_count<<<NEDGE / 256, 256, 0, stream>>>(dstA, cnt, NEDGE);
    k_scan<<<1, 256, 0, stream>>>(cnt, row_start, cursor, dinv);
    k_fill_csr2<<<NEDGE / 256, 256, 0, stream>>>(srcA, dstA, cursor, dinv, slist, wlist, NEDGE);

    // fused GEMM: xs @ [Win | Wc] -> l1 (relu, split) + hc (bf16)
    k_gemm128_A<<<768, 256, 0, stream>>>(
        xsh, xsl, wAt_h, wAt_l, b_in_self, l1h, l1l, hcb);

    // double aggregation (wave-per-node, bf16 tables): t1 = S hc ; g2 = S t1 + svec*bc + gb2
    k_agg4<0><<<NNODE / 4, 256, 0, stream>>>(row_start, slist, wlist, dinv, hcb,
                                             nullptr, nullptr, t1b, nullptr, nullptr);
    k_agg4<1><<<NNODE / 4, 256, 0, stream>>>(row_start, slist, wlist, dinv, t1b,
                                             bc, gb2, nullptr, g2h, g2l);

    // z = [ [xs|l1]@wost + b_os , [xn|g2]@wot + b_o ]  (fp32)
    k_gemm128_Z<<<512, 256, 0, stream>>>(
        xsh, xsl, l1h, l1l, xnh, xnl, g2h, g2l,
        wost_h, wost_l, wot_h, wot_l, b_out_self, b_out, zf);

    // quantize z -> i8 hi/lo + per-row scales
    k_quant<<<NNODE / 4, 256, 0, stream>>>(zf, qa, qb, scl);

    // out = sigmoid(z z^T), split-i8 MFMA pipeline
    k_zzt_q8<<<2080, 256, 0, stream>>>(qa, qb, scl, out);
}